// Round 5
// baseline (1670.725 us; speedup 1.0000x reference)
//
#include <hip/hip_runtime.h>
#include <math.h>

#define BB 4
#define SS 256
#define DD 300
#define DP 304   // DD padded to multiple of 16
#define EE 128
#define LL 20
#define H3 384
#define D2 256   // 2E
#define D12 1536 // 12E

typedef __attribute__((ext_vector_type(8)))  short short8;
typedef __attribute__((ext_vector_type(16))) float f32x16;
typedef __attribute__((ext_vector_type(4)))  float f32x4;
typedef __attribute__((ext_vector_type(4)))  unsigned int u32x4;

__device__ __forceinline__ float tanh_fast(float x){
  float e = __expf(2.f*x);
  return 1.f - 2.f/(e+1.f);
}
__device__ __forceinline__ float sigmoidf_(float x){ return 1.f/(1.f+__expf(-x)); }
__device__ __forceinline__ float bf16_to_f(unsigned u){ return __builtin_bit_cast(float, u<<16); }
__device__ __forceinline__ float bf16hi_to_f(unsigned u){ return __builtin_bit_cast(float, u & 0xFFFF0000u); }
__device__ __forceinline__ unsigned bf16_rne(float f){
  unsigned u = __builtin_bit_cast(unsigned, f);
  return (u + 0x7FFFu + ((u>>16)&1u)) >> 16;
}
__device__ __forceinline__ unsigned pack_bf16x2(float lo, float hi){
  return bf16_rne(lo) | (bf16_rne(hi)<<16);
}

// ---------------- f32 -> bf16 (RNE), 2 elems/thread ----------------
__global__ void k_cvt_bf16(const float* __restrict__ src, unsigned short* __restrict__ dst, int n2){
  int i = blockIdx.x*blockDim.x + threadIdx.x;
  if (i < n2){
    float2 f = *(const float2*)(src + 2*i);
    *(unsigned*)(dst + 2*i) = pack_bf16x2(f.x, f.y);
  }
}

// ---------------- fused weight conversion (13 segments, K-padding aware) ----------------
struct CvtSeg { const float* src; unsigned short* dst; int rows, Ks, Kd; };
struct CvtArgs { CvtSeg s[13]; };
__global__ void k_cvt_weights(CvtArgs a){
  CvtSeg sg = a.s[blockIdx.y];
  int p = blockIdx.x*256 + threadIdx.x;          // dst pair index
  int Kd2 = sg.Kd>>1;
  int npairs = sg.rows*Kd2;
  if (p >= npairs) return;
  int row = p/Kd2, kk = (p - row*Kd2)*2;
  float f0 = (kk   < sg.Ks)? sg.src[(size_t)row*sg.Ks+kk  ] : 0.f;
  float f1 = (kk+1 < sg.Ks)? sg.src[(size_t)row*sg.Ks+kk+1] : 0.f;
  *(unsigned*)(sg.dst + (size_t)row*sg.Kd + kk) = pack_bf16x2(f0,f1);
}

// ---------------- embedding gather -> padded bf16 ----------------
__global__ void k_embed(const int* __restrict__ inp, const float* __restrict__ emb,
                        unsigned short* __restrict__ xb){
  int row = blockIdx.x;            // b*S+s
  int idx = inp[row];
  const float* src = emb + (size_t)idx*DD;
  unsigned short* dst = xb + (size_t)row*DP;
  int p = threadIdx.x;             // pair index, 152 pairs
  if (p < DP/2){
    float f0 = (2*p   < DD)? src[2*p  ] : 0.f;
    float f1 = (2*p+1 < DD)? src[2*p+1] : 0.f;
    *(unsigned*)(dst + 2*p) = pack_bf16x2(f0,f1);
  }
}

// ---------------- init gx pair with input-projection biases ----------------
__global__ void k_init2(float* __restrict__ gf, const float* __restrict__ bf,
                        float* __restrict__ gb, const float* __restrict__ bb){
  int row = blockIdx.x, n = threadIdx.x;   // block = H3 threads
  gf[(size_t)row*H3+n] = bf[n];
  gb[(size_t)row*H3+n] = bb[n];
}

// ---------------- bf16 MFMA matmul: out[M,N] (+)= X[M,K] @ W[N,K]^T ----------------
__global__ __launch_bounds__(64) void k_mmbf(
    const unsigned short* __restrict__ X, const unsigned short* __restrict__ W,
    const float* __restrict__ bias, float* __restrict__ out,
    int N, int K, int kspan){
  int lane=threadIdx.x, col=lane&31, half=lane>>5;
  int n0=blockIdx.x*32, m0=blockIdx.y*64;
  int ks=blockIdx.z*kspan, ke=ks+kspan; if (ke>K) ke=K;
  const unsigned short* pa0 = X + (size_t)(m0+col)*K + half*8;
  const unsigned short* pa1 = pa0 + (size_t)32*K;
  const unsigned short* pb  = W + (size_t)(n0+col)*K + half*8;
  f32x16 acc0={}, acc1={};
  #pragma unroll 2
  for (int k=ks;k<ke;k+=16){
    short8 a0=__builtin_bit_cast(short8, *(const uint4*)(pa0+k));
    short8 a1=__builtin_bit_cast(short8, *(const uint4*)(pa1+k));
    short8 bv=__builtin_bit_cast(short8, *(const uint4*)(pb +k));
    acc0=__builtin_amdgcn_mfma_f32_32x32x16_bf16(a0,bv,acc0,0,0,0);
    acc1=__builtin_amdgcn_mfma_f32_32x32x16_bf16(a1,bv,acc1,0,0,0);
  }
  int cn = n0+col;
  if (gridDim.z==1){
    float bn = bias? bias[cn] : 0.f;
    #pragma unroll
    for (int r=0;r<16;r++){
      int row=(r&3)+8*(r>>2)+4*half;
      out[(size_t)(m0+row)*N+cn]    = acc0[r]+bn;
      out[(size_t)(m0+32+row)*N+cn] = acc1[r]+bn;
    }
  } else {
    #pragma unroll
    for (int r=0;r<16;r++){
      int row=(r&3)+8*(r>>2)+4*half;
      atomicAdd(&out[(size_t)(m0+row)*N+cn],    acc0[r]);
      atomicAdd(&out[(size_t)(m0+32+row)*N+cn], acc1[r]);
    }
  }
}

// ---------------- GRU scan: MFMA recurrence, raw-barrier pipelined ----------------
// Round-4 structure (swapped-operand MFMA, weights in 48 VGPRs, conflict-free
// 68-word-stride hbuf) + the round-4 lesson: __syncthreads() drains
// vmcnt(0), exposing ~900cy cold-HBM gx latency EVERY step. Here the barrier
// is raw: sched_barrier + s_waitcnt lgkmcnt(0) + s_barrier — only the 8.7KB
// LDS h-traffic is ordered; gx loads and out stores float across barriers
// with compiler-counted vmcnt at use. gx is prefetched DEPTH-2 (4 static
// register sets, 4-unrolled loop): issued at top of step t, consumed at
// gates of t+2 -> ~2 steps (~1000cy) of latency cover.
__global__ __launch_bounds__(512, 1) void k_gru_scan(
                          const float* __restrict__ gxf, const float* __restrict__ gxb,
                          const float* __restrict__ whhf, const float* __restrict__ whhb,
                          const float* __restrict__ bhhf, const float* __restrict__ bhhb,
                          const float* __restrict__ h0,
                          float* __restrict__ out,
                          float* __restrict__ hT){
  int dir = blockIdx.x, tid = threadIdx.x;
  const float* gx  = dir? gxb : gxf;
  const float* whh = dir? whhb : whhf;
  const float* bhh = dir? bhhb : bhhf;
  int w = tid>>6, lane = tid&63;
  int q = lane>>4, c = lane&15;          // k-quarter, col-in-tile
  bool act = (c < BB);                   // active lanes own (batch=c, 4 rows)
  int b = c;
  int rbase = w*16 + 4*q;                // first of this lane's 4 rows

  // ---- A fragments: weights, 3 tiles x 4 k-tiles, register-resident ----
  short8 wfr[3][4];
  {
    const int tiles[3] = {w, w+8, w+16};
    #pragma unroll
    for (int ti=0; ti<3; ti++){
      const float* wr = whh + (size_t)(tiles[ti]*16 + c)*EE + q*8;
      #pragma unroll
      for (int kt=0; kt<4; kt++){
        float4 f0 = *(const float4*)(wr + kt*32);
        float4 f1 = *(const float4*)(wr + kt*32 + 4);
        u32x4 pk;
        pk.x = pack_bf16x2(f0.x, f0.y); pk.y = pack_bf16x2(f0.z, f0.w);
        pk.z = pack_bf16x2(f1.x, f1.y); pk.w = pack_bf16x2(f1.z, f1.w);
        asm volatile("" : "+v"(pk));   // opaque: no remat, stays in VGPRs
        wfr[ti][kt] = __builtin_bit_cast(short8, pk);
      }
    }
  }

  __shared__ float hbuf[2*1088];
  for (int i=tid; i<2*1088; i+=512) hbuf[i] = 0.f;

  f32x4 br={}, bz={}, bn={}, hp={};
  if (act){
    br = *(const f32x4*)&bhh[rbase];
    bz = *(const f32x4*)&bhh[EE + rbase];
    bn = *(const f32x4*)&bhh[2*EE + rbase];
    if (h0) hp = *(const f32x4*)&h0[((size_t)dir*BB+b)*EE + rbase];
  }
  int g = 2*w + (q>>1);
  int wword = g*68 + b*4 + (q&1)*2;      // this lane's 2-dword slot
  __syncthreads();                       // zero-init done before packing
  if (act){
    unsigned u0 = pack_bf16x2(hp[0], hp[1]);
    unsigned u1 = pack_bf16x2(hp[2], hp[3]);
    *(uint2*)&hbuf[wword] = make_uint2(u0, u1);
  }
  // prologue: preload gx for t=0 (set0) and t=1 (set1)
  f32x4 g0a={},g0b={},g0c={}, g1a={},g1b={},g1c={}, g2a={},g2b={},g2c={}, g3a={},g3b={},g3c={};
  if (act){
    int s0 = dir? (SS-1) : 0;
    int s1 = dir? (SS-2) : 1;
    const float* gp0 = gx + ((size_t)b*SS+s0)*H3 + rbase;
    const float* gp1 = gx + ((size_t)b*SS+s1)*H3 + rbase;
    g0a=*(const f32x4*)(gp0); g0b=*(const f32x4*)(gp0+EE); g0c=*(const f32x4*)(gp0+2*EE);
    g1a=*(const f32x4*)(gp1); g1b=*(const f32x4*)(gp1+EE); g1c=*(const f32x4*)(gp1+2*EE);
  }
  __syncthreads();

  auto step = [&](int t, f32x4& gc0, f32x4& gc1, f32x4& gc2,
                         f32x4& gp0, f32x4& gp1, f32x4& gp2){
    int s = dir? (SS-1-t) : t;
    // depth-2 prefetch: issue loads for t+2 at the top (float across barriers)
    if (act && t+2 < SS){
      int sp = dir? (SS-3-t) : (t+2);
      const float* gp = gx + ((size_t)b*SS+sp)*H3 + rbase;
      gp0 = *(const f32x4*)(gp);
      gp1 = *(const f32x4*)(gp + EE);
      gp2 = *(const f32x4*)(gp + 2*EE);
    }
    // B fragments: current h
    const float* hb = &hbuf[(t&1)*1088];
    short8 hfr[4];
    #pragma unroll
    for (int kt=0; kt<4; kt++)
      hfr[kt] = __builtin_bit_cast(short8, *(const u32x4*)&hb[(kt*4+q)*68 + c*4]);
    // 12 MFMA, 6 independent 2-deep chains
    f32x4 aR0={},aZ0={},aN0={},aR1={},aZ1={},aN1={};
    aR0 = __builtin_amdgcn_mfma_f32_16x16x32_bf16(wfr[0][0], hfr[0], aR0,0,0,0);
    aZ0 = __builtin_amdgcn_mfma_f32_16x16x32_bf16(wfr[1][0], hfr[0], aZ0,0,0,0);
    aN0 = __builtin_amdgcn_mfma_f32_16x16x32_bf16(wfr[2][0], hfr[0], aN0,0,0,0);
    aR1 = __builtin_amdgcn_mfma_f32_16x16x32_bf16(wfr[0][2], hfr[2], aR1,0,0,0);
    aZ1 = __builtin_amdgcn_mfma_f32_16x16x32_bf16(wfr[1][2], hfr[2], aZ1,0,0,0);
    aN1 = __builtin_amdgcn_mfma_f32_16x16x32_bf16(wfr[2][2], hfr[2], aN1,0,0,0);
    aR0 = __builtin_amdgcn_mfma_f32_16x16x32_bf16(wfr[0][1], hfr[1], aR0,0,0,0);
    aZ0 = __builtin_amdgcn_mfma_f32_16x16x32_bf16(wfr[1][1], hfr[1], aZ0,0,0,0);
    aN0 = __builtin_amdgcn_mfma_f32_16x16x32_bf16(wfr[2][1], hfr[1], aN0,0,0,0);
    aR1 = __builtin_amdgcn_mfma_f32_16x16x32_bf16(wfr[0][3], hfr[3], aR1,0,0,0);
    aZ1 = __builtin_amdgcn_mfma_f32_16x16x32_bf16(wfr[1][3], hfr[3], aZ1,0,0,0);
    aN1 = __builtin_amdgcn_mfma_f32_16x16x32_bf16(wfr[2][3], hfr[3], aN1,0,0,0);
    f32x4 aR = aR0+aR1, aZ = aZ0+aZ1, aN = aN0+aN1;
    // gates: 4 rows x 1 batch per active lane, all in-register
    if (act){
      f32x4 h2;
      #pragma unroll
      for (int i=0;i<4;i++){
        float rg = sigmoidf_(gc0[i] + aR[i] + br[i]);
        float zg = sigmoidf_(gc1[i] + aZ[i] + bz[i]);
        float ng = tanh_fast (gc2[i] + rg*(aN[i] + bn[i]));
        h2[i] = (1.f-zg)*ng + zg*hp[i];
      }
      hp = h2;
      *(f32x4*)&out[((size_t)b*SS+s)*D2 + (size_t)dir*EE + rbase] = h2;
      unsigned u0 = pack_bf16x2(h2[0], h2[1]);
      unsigned u1 = pack_bf16x2(h2[2], h2[3]);
      *(uint2*)&hbuf[((t+1)&1)*1088 + wword] = make_uint2(u0, u1);
    }
    // raw barrier: order ONLY the LDS h-traffic; gx/out stay in flight
    __builtin_amdgcn_sched_barrier(0);
    asm volatile("s_waitcnt lgkmcnt(0)" ::: "memory");
    __builtin_amdgcn_s_barrier();
    __builtin_amdgcn_sched_barrier(0);
  };

  for (int t=0; t<SS; t+=4){
    step(t,   g0a,g0b,g0c, g2a,g2b,g2c);   // consume set0, prefetch t+2 -> set2
    step(t+1, g1a,g1b,g1c, g3a,g3b,g3c);   // consume set1, prefetch t+3 -> set3
    step(t+2, g2a,g2b,g2c, g0a,g0b,g0c);   // consume set2, prefetch t+4 -> set0
    step(t+3, g3a,g3b,g3c, g1a,g1b,g1c);   // consume set3, prefetch t+5 -> set1
  }
  if (hT && act) *(f32x4*)&hT[((size_t)dir*BB+b)*EE + rbase] = hp;
}

__global__ void k_copy_hq(const unsigned short* __restrict__ hqb, unsigned short* __restrict__ aggb){
  int row=blockIdx.x;
  aggb[(size_t)row*D12 + threadIdx.x] = hqb[(size_t)row*D2 + threadIdx.x];
}

// --------- block softmax over 256 values ---------
__device__ __forceinline__ void softmax256(float val, float* red, float* p){
  int tid=threadIdx.x;
  red[tid]=val; __syncthreads();
  for (int st=128; st>0; st>>=1){ if (tid<st) red[tid]=fmaxf(red[tid],red[tid+st]); __syncthreads(); }
  float mx=red[0]; __syncthreads();
  float ex=__expf(val-mx); red[tid]=ex; __syncthreads();
  for (int st=128; st>0; st>>=1){ if (tid<st) red[tid]+=red[tid+st]; __syncthreads(); }
  float inv=1.f/red[0];
  p[tid]=ex*inv; __syncthreads();
}

// ---------------- additive-style attention (ptc: +1, ptm: -1), bf16 out ----------------
__global__ __launch_bounds__(256) void k_attn_add(const float* __restrict__ A, const float* __restrict__ Bq,
                          const float* __restrict__ v, float sign,
                          const float* __restrict__ V, unsigned short* __restrict__ aggout, int off){
  __shared__ __align__(16) float bq[EE];
  __shared__ __align__(16) float vv[EE];
  __shared__ float p[SS]; __shared__ float red[SS];
  int q=blockIdx.x, b=blockIdx.y, tid=threadIdx.x;
  if (tid<EE){ bq[tid]=sign*Bq[((size_t)b*SS+q)*EE+tid]; vv[tid]=v[tid]; }
  __syncthreads();
  const float* Ar = A + ((size_t)b*SS+tid)*EE;
  float s=0.f;
  #pragma unroll
  for (int e=0;e<EE;e+=4){
    float4 a=*(const float4*)(Ar+e);
    float4 bb=*(const float4*)(bq+e);
    float4 vw=*(const float4*)(vv+e);
    s += vw.x*tanh_fast(a.x+bb.x)+vw.y*tanh_fast(a.y+bb.y)+vw.z*tanh_fast(a.z+bb.z)+vw.w*tanh_fast(a.w+bb.w);
  }
  softmax256(s, red, p);
  const float* V0 = V + (size_t)b*SS*D2;
  float o=0.f;
  for (int k=0;k<SS;k++) o += p[k]*V0[(size_t)k*D2+tid];
  aggout[((size_t)b*SS+q)*D12 + off + tid] = (unsigned short)bf16_rne(o);
}

// ---------------- bilinear attention (ptb), bf16 out ----------------
__global__ __launch_bounds__(256) void k_attn_bil(const float* __restrict__ Pb, const float* __restrict__ hq,
                          const float* __restrict__ V, unsigned short* __restrict__ aggout, int off){
  __shared__ __align__(16) float hqq[D2];
  __shared__ float p[SS]; __shared__ float red[SS];
  int q=blockIdx.x, b=blockIdx.y, tid=threadIdx.x;
  hqq[tid]=hq[((size_t)b*SS+q)*D2+tid];
  __syncthreads();
  const float* Pr = Pb + ((size_t)b*SS+tid)*D2;
  float s=0.f;
  #pragma unroll
  for (int d=0;d<D2;d+=4){
    float4 a=*(const float4*)(Pr+d);
    float4 hh=*(const float4*)(hqq+d);
    s += a.x*hh.x+a.y*hh.y+a.z*hh.z+a.w*hh.w;
  }
  softmax256(s, red, p);
  const float* V0 = V + (size_t)b*SS*D2;
  float o=0.f;
  for (int k=0;k<SS;k++) o += p[k]*V0[(size_t)k*D2+tid];
  aggout[((size_t)b*SS+q)*D12 + off + tid] = (unsigned short)bf16_rne(o);
}

// ------- fused ptd/pts: MFMA scores + tanh/v reduce + softmax + PV, bf16 out -------
__global__ __launch_bounds__(256, 2) void k_mulattn_fused(
    const unsigned short* __restrict__ keysb,
    const float* __restrict__ qm,
    const unsigned short* __restrict__ Wb,
    const float* __restrict__ v,
    const float* __restrict__ V,
    unsigned short* __restrict__ aggout, int off){
  __shared__ __align__(16) float qrow[D2];
  __shared__ __align__(16) float vrow[EE];
  __shared__ float scq[SS];
  __shared__ float red[SS];
  __shared__ float p[SS];
  int q=blockIdx.x, b=blockIdx.y, tid=threadIdx.x;
  int wave=tid>>6, lane=tid&63;
  size_t bS = (size_t)b*SS;
  qrow[tid]=qm[(bS+q)*D2+tid];
  if (tid<EE) vrow[tid]=v[tid];
  __syncthreads();

  f32x16 acc[2][4]={};
  int m0 = wave*64;
  int col = lane&31, half = lane>>5;
  const unsigned short* krow0 = keysb + (bS + m0 + col)*D2 + half*8;
  const unsigned short* krow1 = krow0 + 32*D2;
  const unsigned short* wrow[4];
  #pragma unroll
  for (int n=0;n<4;n++) wrow[n] = Wb + (size_t)(n*32+col)*D2 + half*8;

  for (int d0=0; d0<D2; d0+=16){
    float4 qsA = *(const float4*)&qrow[d0 + half*8];
    float4 qsB = *(const float4*)&qrow[d0 + half*8 + 4];
    short8 bfrag[4];
    #pragma unroll
    for (int n=0;n<4;n++) bfrag[n] = __builtin_bit_cast(short8, *(const uint4*)(wrow[n]+d0));
    #pragma unroll
    for (int i=0;i<2;i++){
      uint4 raw = *(const uint4*)((i? krow1:krow0) + d0);
      float f0=bf16_to_f(raw.x)*qsA.x, f1=bf16hi_to_f(raw.x)*qsA.y;
      float f2=bf16_to_f(raw.y)*qsA.z, f3=bf16hi_to_f(raw.y)*qsA.w;
      float f4=bf16_to_f(raw.z)*qsB.x, f5=bf16hi_to_f(raw.z)*qsB.y;
      float f6=bf16_to_f(raw.w)*qsB.z, f7=bf16hi_to_f(raw.w)*qsB.w;
      uint4 pk;
      pk.x=pack_bf16x2(f0,f1);
      pk.y=pack_bf16x2(f2,f3);
      pk.z=pack_bf16x2(f4,f5);
      pk.w=pack_bf16x2(f6,f7);
      short8 afrag = __builtin_bit_cast(short8, pk);
      #pragma unroll
      for (int n=0;n<4;n++)
        acc[i][n] = __builtin_amdgcn_mfma_f32_32x32x16_bf16(afrag, bfrag[n], acc[i][n], 0,0,0);
    }
  }
  float vn[4];
  #pragma unroll
  for (int n=0;n<4;n++) vn[n]=vrow[n*32+col];
  #pragma unroll
  for (int i=0;i<2;i++){
    #pragma unroll
    for (int r=0;r<16;r++){
      float s = vn[0]*tanh_fast(acc[i][0][r]) + vn[1]*tanh_fast(acc[i][1][r])
              + vn[2]*tanh_fast(acc[i][2][r]) + vn[3]*tanh_fast(acc[i][3][r]);
      s += __shfl_xor(s,1,32); s += __shfl_xor(s,2,32); s += __shfl_xor(s,4,32);
      s += __shfl_xor(s,8,32); s += __shfl_xor(s,16,32);
      int k = m0 + i*32 + (r&3) + 8*(r>>2) + 4*half;
      scq[k] = s;
    }
  }
  __syncthreads();
  float val = scq[tid];
  softmax256(val, red, p);
  const float* V0 = V + bS*D2;
  float o=0.f;
  for (int k=0;k<SS;k++) o += p[k]*V0[(size_t)k*D2+tid];
  aggout[(bS+q)*D12 + off + tid] = (unsigned short)bf16_rne(o);
}

// ---------------- rl pooling over hq + folded sB = rl @ Wc2^T ----------------
__global__ __launch_bounds__(256) void k_rl(const float* __restrict__ spj, const float* __restrict__ hq,
                    const float* __restrict__ vp, const float* __restrict__ Wc2,
                    float* __restrict__ sB){
  __shared__ __align__(16) float vpl[EE];
  __shared__ float p[SS]; __shared__ float red[SS];
  __shared__ __align__(16) float rr[D2];
  int b=blockIdx.x, tid=threadIdx.x;
  if (tid<EE) vpl[tid]=vp[tid];
  __syncthreads();
  const float* row = spj + ((size_t)b*SS+tid)*EE;
  float sj=0.f;
  #pragma unroll
  for (int e=0;e<EE;e+=4){
    float4 a=*(const float4*)(row+e);
    float4 vw=*(const float4*)(vpl+e);
    sj += vw.x*tanh_fast(a.x)+vw.y*tanh_fast(a.y)+vw.z*tanh_fast(a.z)+vw.w*tanh_fast(a.w);
  }
  softmax256(sj, red, p);
  float o=0.f;
  for (int s=0;s<SS;s++) o += p[s]*hq[((size_t)b*SS+s)*D2+tid];
  rr[tid]=o; __syncthreads();
  if (tid<EE){
    const float* wr = Wc2 + (size_t)tid*D2;
    float a=0.f;
    #pragma unroll
    for (int d=0;d<D2;d+=4){
      float4 w4=*(const float4*)(wr+d);
      float4 r4=*(const float4*)(rr+d);
      a += w4.x*r4.x+w4.y*r4.y+w4.z*r4.z+w4.w*r4.w;
    }
    sB[(size_t)b*EE+tid]=a;
  }
}

// ---------------- final pooling + prediction ----------------
__global__ __launch_bounds__(256) void k_final(const float* __restrict__ sA, const float* __restrict__ sB,
                       const float* __restrict__ vc, const float* __restrict__ agg_rep,
                       const float* __restrict__ Wpred, float* __restrict__ out){
  __shared__ __align__(16) float sBl[EE];
  __shared__ __align__(16) float vcl[EE];
  __shared__ float p[SS]; __shared__ float red[SS]; __shared__ float rr[D2];
  int b=blockIdx.x, tid=threadIdx.x;
  if (tid<EE){ sBl[tid]=sB[(size_t)b*EE+tid]; vcl[tid]=vc[tid]; }
  __syncthreads();
  const float* rowA = sA + ((size_t)b*SS+tid)*EE;
  float sc=0.f;
  #pragma unroll
  for (int e=0;e<EE;e+=4){
    float4 a=*(const float4*)(rowA+e);
    float4 bb=*(const float4*)(sBl+e);
    float4 vw=*(const float4*)(vcl+e);
    sc += vw.x*(a.x+bb.x)+vw.y*(a.y+bb.y)+vw.z*(a.z+bb.z)+vw.w*(a.w+bb.w);
  }
  softmax256(sc, red, p);
  float o=0.f;
  for (int s=0;s<SS;s++) o += p[s]*agg_rep[((size_t)b*SS+s)*D2+tid];
  rr[tid]=o; __syncthreads();
  if (tid<LL){
    float a=0.f;
    const float* wr = Wpred + (size_t)tid*D2;
    for (int d=0;d<D2;d++) a += wr[d]*rr[d];
    out[(size_t)b*LL+tid]=sigmoidf_(a);
  }
}

extern "C" void kernel_launch(void* const* d_in, const int* in_sizes, int n_in,
                              void* d_out, int out_size, void* d_ws, size_t ws_size,
                              hipStream_t stream){
  (void)in_sizes; (void)n_in; (void)out_size; (void)ws_size;
  const int*   inp = (const int*)d_in[0];
  const float* emb = (const float*)d_in[1];
  const float* enc_wih_f=(const float*)d_in[2],  *enc_whh_f=(const float*)d_in[3],
             *enc_bih_f=(const float*)d_in[4],  *enc_bhh_f=(const float*)d_in[5];
  const float* enc_wih_b=(const float*)d_in[6],  *enc_whh_b=(const float*)d_in[7],
             *enc_bih_b=(const float*)d_in[8],  *enc_bhh_b=(const float*)d_in[9];
  const float* hid_wih_f=(const float*)d_in[10], *hid_whh_f=(const float*)d_in[11],
             *hid_bih_f=(const float*)d_in[12], *hid_bhh_f=(const float*)d_in[13];
  const float* hid_wih_b=(const float*)d_in[14], *hid_whh_b=(const float*)d_in[15],
             *hid_bih_b=(const float*)d_in[16], *hid_bhh_b=(const float*)d_in[17];
  const float* agg_wih_f=(const float*)d_in[18], *agg_whh_f=(const float*)d_in[19],
             *agg_bih_f=(const float*)d_in[20], *agg_bhh_f=(const float*)d_in[21];
  const float* agg_wih_b=(const float*)d_in[22], *agg_whh_b=(const float*)d_in[23],
             *agg_bih_b=(const float*)d_in[24], *agg_bhh_b=(const float*)d_in[25];
  const float* Wc1=(const float*)d_in[26], *Wc2=(const float*)d_in[27], *vc=(const float*)d_in[28];
  const float* Wb =(const float*)d_in[29];
  const float* Wd =(const float*)d_in[30], *vd=(const float*)d_in[31];
  const float* Wm =(const float*)d_in[32], *vm=(const float*)d_in[33];
  const float* Ws =(const float*)d_in[34], *vs=(const float*)d_in[35];
  const float* Wp =(const float*)d_in[36], *vp=(const float*)d_in[37];
  const float* Wpred=(const float*)d_in[38];

  float* ws = (float*)d_ws;
  size_t o = 0;
  float* gxf     = ws + o; o += (size_t)BB*SS*H3;
  float* gxb     = ws + o; o += (size_t)BB*SS*H3;
  float* hp      = ws + o; o += (size_t)BB*SS*D2;
  float* hq      = ws + o; o += (size_t)BB*SS*D2;
  float* hidden  = ws + o; o += (size_t)2*BB*EE;
  float* s1      = ws + o; o += (size_t)BB*SS*EE;
  float* s2      = ws + o; o += (size_t)BB*SS*EE;
  float* Am      = ws + o; o += (size_t)BB*SS*EE;
  float* Bm      = ws + o; o += (size_t)BB*SS*EE;
  float* Pb      = ws + o; o += (size_t)BB*SS*D2;
  float* spj     = ws + o; o += (size_t)BB*SS*EE;
  float* agg_rep = ws + o; o += (size_t)BB*SS*D2;
  float* sA      = ws + o; o += (size_t)BB*SS*EE;
  float* sB      = ws + o; o += (size_t)BB*EE;
  // bf16 buffers (ushort counts, all even -> advance o by count/2)
  unsigned short* x_bf      = (unsigned short*)(ws+o); o += (size_t)BB*SS*DP/2;
  unsigned short* hp_bf     = (unsigned short*)(ws+o); o += (size_t)BB*SS*D2/2;
  unsigned short* hq_bf     = (unsigned short*)(ws+o); o += (size_t)BB*SS*D2/2;
  unsigned short* agg_bf    = (unsigned short*)(ws+o); o += (size_t)BB*SS*D12/2;
  unsigned short* aggrep_bf = (unsigned short*)(ws+o); o += (size_t)BB*SS*D2/2;
  unsigned short* encf_bf   = (unsigned short*)(ws+o); o += (size_t)H3*DP/2;
  unsigned short* encb_bf   = (unsigned short*)(ws+o); o += (size_t)H3*DP/2;
  unsigned short* hidf_bf   = (unsigned short*)(ws+o); o += (size_t)H3*D2/2;
  unsigned short* hidb_bf   = (unsigned short*)(ws+o); o += (size_t)H3*D2/2;
  unsigned short* aggf_bf   = (unsigned short*)(ws+o); o += (size_t)H3*D12/2;
  unsigned short* aggb_bf   = (unsigned short*)(ws+o); o += (size_t)H3*D12/2;
  unsigned short* Wc1_bf    = (unsigned short*)(ws+o); o += (size_t)EE*D2/2;
  unsigned short* Wc2_bf    = (unsigned short*)(ws+o); o += (size_t)EE*D2/2;
  unsigned short* Wm_bf     = (unsigned short*)(ws+o); o += (size_t)EE*D2/2;
  unsigned short* Wb_bf     = (unsigned short*)(ws+o); o += (size_t)D2*D2/2;
  unsigned short* Wp_bf     = (unsigned short*)(ws+o); o += (size_t)EE*D2/2;
  unsigned short* Wd_bf     = (unsigned short*)(ws+o); o += (size_t)EE*D2/2;
  unsigned short* Ws_bf     = (unsigned short*)(ws+o); o += (size_t)EE*D2/2;

  const int M = BB*SS; // 1024
  auto mmbf=[&](const unsigned short* X,const unsigned short* W,const float* bias,
                float* outp,int N,int K,int z,int kspan){
    dim3 g(N/32, M/64, z);
    k_mmbf<<<g,64,0,stream>>>(X,W,bias,outp,N,K,kspan);
  };

  // ---- input prep ----
  k_embed<<<M,256,0,stream>>>(inp, emb, x_bf);
  CvtArgs ca;
  ca.s[0]  = {enc_wih_f, encf_bf, H3, DD, DP};
  ca.s[1]  = {enc_wih_b, encb_bf, H3, DD, DP};
  ca.s[2]  = {hid_wih_f, hidf_bf, H3, D2, D2};
  ca.s[3]  = {hid_wih_b, hidb_bf, H3, D2, D2};
  ca.s[4]  = {agg_wih_f, aggf_bf, H3, D12, D12};
  ca.s[5]  = {agg_wih_b, aggb_bf, H3, D12, D12};
  ca.s[6]  = {Wc1, Wc1_bf, EE, D2, D2};
  ca.s[7]  = {Wc2, Wc2_bf, EE, D2, D2};
  ca.s[8]  = {Wm,  Wm_bf,  EE, D2, D2};
  ca.s[9]  = {Wb,  Wb_bf,  D2, D2, D2};
  ca.s[10] = {Wp,  Wp_bf,  EE, D2, D2};
  ca.s[11] = {Wd,  Wd_bf,  EE, D2, D2};
  ca.s[12] = {Ws,  Ws_bf,  EE, D2, D2};
  {
    int maxpairs = H3*D12/2;  // 294912
    dim3 g((maxpairs+255)/256, 13);
    k_cvt_weights<<<g,256,0,stream>>>(ca);
  }

  // ---- encoder BiGRU ----
  k_init2<<<M,H3,0,stream>>>(gxf, enc_bih_f, gxb, enc_bih_b);
  mmbf(x_bf, encf_bf, nullptr, gxf, H3, DP, 4, 80);
  mmbf(x_bf, encb_bf, nullptr, gxb, H3, DP, 4, 80);
  k_gru_scan<<<dim3(2),512,0,stream>>>(gxf,gxb,enc_whh_f,enc_whh_b,enc_bhh_f,enc_bhh_b,
                                       nullptr,hp,hidden);
  k_cvt_bf16<<<(M*D2/2+255)/256,256,0,stream>>>(hp, hp_bf, M*D2/2);

  // ---- hidden BiGRU ----
  k_init2<<<M,H3,0,stream>>>(gxf, hid_bih_f, gxb, hid_bih_b);
  mmbf(hp_bf, hidf_bf, nullptr, gxf, H3, D2, 4, 64);
  mmbf(hp_bf, hidb_bf, nullptr, gxb, H3, D2, 4, 64);
  k_gru_scan<<<dim3(2),512,0,stream>>>(gxf,gxb,hid_whh_f,hid_whh_b,hid_bhh_f,hid_bhh_b,
                                       hidden,hq,nullptr);
  k_cvt_bf16<<<(M*D2/2+255)/256,256,0,stream>>>(hq, hq_bf, M*D2/2);

  // ---- projections (ksplit=1, direct store) ----
  mmbf(hp_bf, Wc1_bf, nullptr, s1,  EE, D2, 1, D2);
  mmbf(hq_bf, Wc2_bf, nullptr, s2,  EE, D2, 1, D2);
  mmbf(hp_bf, Wm_bf,  nullptr, Am,  EE, D2, 1, D2);
  mmbf(hq_bf, Wm_bf,  nullptr, Bm,  EE, D2, 1, D2);
  mmbf(hp_bf, Wb_bf,  nullptr, Pb,  D2, D2, 1, D2);
  mmbf(hq_bf, Wp_bf,  nullptr, spj, EE, D2, 1, D2);

  // ---- attentions -> agg (bf16). slices: hq(0) pts(256) ptc(512) ptd(768) ptb(1024) ptm(1280)
  k_copy_hq<<<M,256,0,stream>>>(hq_bf, agg_bf);
  dim3 gq(SS,BB);
  k_attn_add<<<gq,256,0,stream>>>(s1,s2,vc, 1.f, hp, agg_bf, 512);
  k_attn_add<<<gq,256,0,stream>>>(Am,Bm,vm,-1.f, hp, agg_bf, 1280);
  k_attn_bil<<<gq,256,0,stream>>>(Pb,hq,hp,agg_bf,1024);
  k_mulattn_fused<<<gq,256,0,stream>>>(hp_bf,hq,Wd_bf,vd,hp,agg_bf,768);
  k_mulattn_fused<<<gq,256,0,stream>>>(hq_bf,hq,Ws_bf,vs,hq,agg_bf,256);

  // ---- aggregation BiGRU ----
  k_init2<<<M,H3,0,stream>>>(gxf, agg_bih_f, gxb, agg_bih_b);
  mmbf(agg_bf, aggf_bf, nullptr, gxf, H3, D12, 8, 192);
  mmbf(agg_bf, aggb_bf, nullptr, gxb, H3, D12, 8, 192);
  k_gru_scan<<<dim3(2),512,0,stream>>>(gxf,gxb,agg_whh_f,agg_whh_b,agg_bhh_f,agg_bhh_b,
                                       nullptr,agg_rep,nullptr);
  k_cvt_bf16<<<(M*D2/2+255)/256,256,0,stream>>>(agg_rep, aggrep_bf, M*D2/2);

  // ---- pooling + prediction ----
  k_rl<<<BB,256,0,stream>>>(spj,hq,vp,Wc2,sB);
  mmbf(aggrep_bf, Wc1_bf, nullptr, sA, EE, D2, 1, D2);
  k_final<<<BB,256,0,stream>>>(sA,sB,vc,agg_rep,Wpred,(float*)d_out);
}

// Round 6
// 1125.735 us; speedup vs baseline: 1.4841x; 1.4841x over previous
//
#include <hip/hip_runtime.h>
#include <math.h>

#define BB 4
#define SS 256
#define DD 300
#define DP 304   // DD padded to multiple of 16
#define EE 128
#define LL 20
#define H3 384
#define D2 256   // 2E
#define D12 1536 // 12E

typedef __attribute__((ext_vector_type(8)))  short short8;
typedef __attribute__((ext_vector_type(16))) float f32x16;
typedef __attribute__((ext_vector_type(2)))  float f32x2;

__device__ __forceinline__ float tanh_fast(float x){
  float e = __expf(2.f*x);
  return 1.f - 2.f/(e+1.f);
}
__device__ __forceinline__ float sigmoidf_(float x){ return 1.f/(1.f+__expf(-x)); }
__device__ __forceinline__ float bf16_to_f(unsigned u){ return __builtin_bit_cast(float, u<<16); }
__device__ __forceinline__ float bf16hi_to_f(unsigned u){ return __builtin_bit_cast(float, u & 0xFFFF0000u); }
__device__ __forceinline__ unsigned bf16_rne(float f){
  unsigned u = __builtin_bit_cast(unsigned, f);
  return (u + 0x7FFFu + ((u>>16)&1u)) >> 16;
}
__device__ __forceinline__ unsigned pack_bf16x2(float lo, float hi){
  return bf16_rne(lo) | (bf16_rne(hi)<<16);
}

// ---------------- f32 -> bf16 (RNE), 2 elems/thread ----------------
__global__ void k_cvt_bf16(const float* __restrict__ src, unsigned short* __restrict__ dst, int n2){
  int i = blockIdx.x*blockDim.x + threadIdx.x;
  if (i < n2){
    float2 f = *(const float2*)(src + 2*i);
    *(unsigned*)(dst + 2*i) = pack_bf16x2(f.x, f.y);
  }
}

// ---------------- fused weight conversion (13 segments, K-padding aware) ----------------
struct CvtSeg { const float* src; unsigned short* dst; int rows, Ks, Kd; };
struct CvtArgs { CvtSeg s[13]; };
__global__ void k_cvt_weights(CvtArgs a){
  CvtSeg sg = a.s[blockIdx.y];
  int p = blockIdx.x*256 + threadIdx.x;          // dst pair index
  int Kd2 = sg.Kd>>1;
  int npairs = sg.rows*Kd2;
  if (p >= npairs) return;
  int row = p/Kd2, kk = (p - row*Kd2)*2;
  float f0 = (kk   < sg.Ks)? sg.src[(size_t)row*sg.Ks+kk  ] : 0.f;
  float f1 = (kk+1 < sg.Ks)? sg.src[(size_t)row*sg.Ks+kk+1] : 0.f;
  *(unsigned*)(sg.dst + (size_t)row*sg.Kd + kk) = pack_bf16x2(f0,f1);
}

// ---------------- embedding gather -> padded bf16 ----------------
__global__ void k_embed(const int* __restrict__ inp, const float* __restrict__ emb,
                        unsigned short* __restrict__ xb){
  int row = blockIdx.x;            // b*S+s
  int idx = inp[row];
  const float* src = emb + (size_t)idx*DD;
  unsigned short* dst = xb + (size_t)row*DP;
  int p = threadIdx.x;             // pair index, 152 pairs
  if (p < DP/2){
    float f0 = (2*p   < DD)? src[2*p  ] : 0.f;
    float f1 = (2*p+1 < DD)? src[2*p+1] : 0.f;
    *(unsigned*)(dst + 2*p) = pack_bf16x2(f0,f1);
  }
}

// ---------------- init gx pair with input-projection biases ----------------
__global__ void k_init2(float* __restrict__ gf, const float* __restrict__ bf,
                        float* __restrict__ gb, const float* __restrict__ bb){
  int row = blockIdx.x, n = threadIdx.x;   // block = H3 threads
  gf[(size_t)row*H3+n] = bf[n];
  gb[(size_t)row*H3+n] = bb[n];
}

// ---------------- bf16 MFMA matmul: out[M,N] (+)= X[M,K] @ W[N,K]^T ----------------
__global__ __launch_bounds__(64) void k_mmbf(
    const unsigned short* __restrict__ X, const unsigned short* __restrict__ W,
    const float* __restrict__ bias, float* __restrict__ out,
    int N, int K, int kspan){
  int lane=threadIdx.x, col=lane&31, half=lane>>5;
  int n0=blockIdx.x*32, m0=blockIdx.y*64;
  int ks=blockIdx.z*kspan, ke=ks+kspan; if (ke>K) ke=K;
  const unsigned short* pa0 = X + (size_t)(m0+col)*K + half*8;
  const unsigned short* pa1 = pa0 + (size_t)32*K;
  const unsigned short* pb  = W + (size_t)(n0+col)*K + half*8;
  f32x16 acc0={}, acc1={};
  #pragma unroll 2
  for (int k=ks;k<ke;k+=16){
    short8 a0=__builtin_bit_cast(short8, *(const uint4*)(pa0+k));
    short8 a1=__builtin_bit_cast(short8, *(const uint4*)(pa1+k));
    short8 bv=__builtin_bit_cast(short8, *(const uint4*)(pb +k));
    acc0=__builtin_amdgcn_mfma_f32_32x32x16_bf16(a0,bv,acc0,0,0,0);
    acc1=__builtin_amdgcn_mfma_f32_32x32x16_bf16(a1,bv,acc1,0,0,0);
  }
  int cn = n0+col;
  if (gridDim.z==1){
    float bn = bias? bias[cn] : 0.f;
    #pragma unroll
    for (int r=0;r<16;r++){
      int row=(r&3)+8*(r>>2)+4*half;
      out[(size_t)(m0+row)*N+cn]    = acc0[r]+bn;
      out[(size_t)(m0+32+row)*N+cn] = acc1[r]+bn;
    }
  } else {
    #pragma unroll
    for (int r=0;r<16;r++){
      int row=(r&3)+8*(r>>2)+4*half;
      atomicAdd(&out[(size_t)(m0+row)*N+cn],    acc0[r]);
      atomicAdd(&out[(size_t)(m0+32+row)*N+cn], acc1[r]);
    }
  }
}

// ---------------- GRU scan (one block per (batch, direction)) ----------------
// Round-2 structure (proven 195us, 0 bank conflicts): 512 threads = 8 waves.
// Wave w owns h-chunk [16w,16w+16); lane owns rows {lane+64i, i=0..5} with
// 16-wide weight slices in registers (packed f32x2 pairs -> v_pk_fma_f32).
// h broadcast via v_readlane -> SGPR (VALU pipes, not the shared LDS pipe).
// Partials through a stride-9 (coprime 32 -> conflict-free) LDS array;
// 128 combine threads do the 8-way sum + gates.
// Round-6 upgrades: (1) DEPTH-2 gx prefetch — comb(t) consumes set A/B and
// immediately reloads the same set for t+2 (register rotation proven live
// in r5's VGPR accounting), covering ~2 steps of HBM latency instead of
// r2's ~0.5-step cover; (2) fused bf16 output store (kills 3 k_cvt passes).
#define GW 8          // dot waves
#define CH 16         // h-chunk per wave = 128/GW
#define PSTR 9        // partial row stride (floats), coprime with 32

__global__ __launch_bounds__(512, 1) void k_gru_scan(
                          const float* __restrict__ gxf, const float* __restrict__ gxb,
                          const float* __restrict__ whhf, const float* __restrict__ whhb,
                          const float* __restrict__ bhhf, const float* __restrict__ bhhb,
                          const float* __restrict__ h0,
                          float* __restrict__ out,
                          unsigned short* __restrict__ out_bf,
                          float* __restrict__ hT){
  int b=blockIdx.x, dir=blockIdx.y, tid=threadIdx.x;
  const float* gx  = dir? gxb : gxf;
  const float* whh = dir? whhb : whhf;
  const float* bhh = dir? bhhb : bhhf;
  int w = tid>>6, lane = tid&63;
  int chunk = w*CH;

  // weights: rows lane+64*(2p), lane+64*(2p+1), chunk slice, packed pairs
  f32x2 wv[3][CH];
  #pragma unroll
  for (int p=0;p<3;p++){
    const float* r0 = whh + (size_t)(lane+64*(2*p  ))*EE + chunk;
    const float* r1 = whh + (size_t)(lane+64*(2*p+1))*EE + chunk;
    #pragma unroll
    for (int k=0;k<CH;k++){ wv[p][k].x = r0[k]; wv[p][k].y = r1[k]; }
  }

  __shared__ __align__(16) float hsh[EE];
  __shared__ float part[H3*PSTR];

  bool comb = (tid < EE);
  float hprev=0.f, b_r=0.f, b_z=0.f, b_n=0.f;
  float xrA=0.f,xzA=0.f,xnA=0.f, xrB=0.f,xzB=0.f,xnB=0.f;
  if (comb){
    int r = tid;
    b_r = bhh[r]; b_z = bhh[r+EE]; b_n = bhh[r+2*EE];
    hprev = h0? h0[((size_t)dir*BB+b)*EE + r] : 0.f;
    hsh[r] = hprev;
    int s0 = dir? (SS-1) : 0;
    int s1 = dir? (SS-2) : 1;
    const float* g0 = gx + ((size_t)b*SS+s0)*H3;
    const float* g1 = gx + ((size_t)b*SS+s1)*H3;
    xrA=g0[r]; xzA=g0[r+EE]; xnA=g0[r+2*EE];
    xrB=g1[r]; xzB=g1[r+EE]; xnB=g1[r+2*EE];
  }
  __syncthreads();

  auto dotphase = [&](){
    float vh = hsh[chunk + (lane & (CH-1))];   // 1 conflict-free ds_read_b32/wave
    f32x2 acc0={0.f,0.f}, acc1={0.f,0.f}, acc2={0.f,0.f};
    #pragma unroll
    for (int k=0;k<CH;k++){
      float s = __builtin_bit_cast(float,
                  __builtin_amdgcn_readlane(__builtin_bit_cast(int, vh), k));
      acc0 += wv[0][k]*s;
      acc1 += wv[1][k]*s;
      acc2 += wv[2][k]*s;
    }
    part[(lane      )*PSTR + w] = acc0.x;
    part[(lane+ 64  )*PSTR + w] = acc0.y;
    part[(lane+128  )*PSTR + w] = acc1.x;
    part[(lane+192  )*PSTR + w] = acc1.y;
    part[(lane+256  )*PSTR + w] = acc2.x;
    part[(lane+320  )*PSTR + w] = acc2.y;
  };

  auto combphase = [&](int t, float xr, float xz, float xn,
                       float& pxr, float& pxz, float& pxn){
    int r = tid;
    float ar=0.f, az=0.f, an=0.f;
    #pragma unroll
    for (int c=0;c<GW;c++){
      ar += part[(r      )*PSTR+c];
      az += part[(r+128  )*PSTR+c];
      an += part[(r+256  )*PSTR+c];
    }
    int s = dir? (SS-1-t) : t;
    float rg = sigmoidf_(xr + ar + b_r);
    float zg = sigmoidf_(xz + az + b_z);
    float ng = tanh_fast(xn + rg*(an + b_n));
    float h2 = (1.f-zg)*ng + zg*hprev;
    hprev = h2;
    hsh[r] = h2;
    size_t oi = ((size_t)b*SS+s)*D2 + (size_t)dir*EE + r;
    out[oi] = h2;
    if (out_bf) out_bf[oi] = (unsigned short)bf16_rne(h2);
    // depth-2 prefetch: reload this set for t+2 (consumed 2 steps from now)
    if (t+2 < SS){
      int sn = dir? (SS-3-t) : (t+2);
      const float* gn = gx + ((size_t)b*SS+sn)*H3;
      pxr=gn[r]; pxz=gn[r+EE]; pxn=gn[r+2*EE];
    }
  };

  for (int t=0;t<SS;t+=2){
    // ---- even step: consume set A ----
    dotphase();
    __syncthreads();
    if (comb) combphase(t, xrA,xzA,xnA, xrA,xzA,xnA);
    __syncthreads();
    // ---- odd step: consume set B ----
    dotphase();
    __syncthreads();
    if (comb) combphase(t+1, xrB,xzB,xnB, xrB,xzB,xnB);
    __syncthreads();
  }
  if (hT && comb) hT[((size_t)dir*BB+b)*EE+tid]=hprev;
}

__global__ void k_copy_hq(const unsigned short* __restrict__ hqb, unsigned short* __restrict__ aggb){
  int row=blockIdx.x;
  aggb[(size_t)row*D12 + threadIdx.x] = hqb[(size_t)row*D2 + threadIdx.x];
}

// --------- block softmax over 256 values ---------
__device__ __forceinline__ void softmax256(float val, float* red, float* p){
  int tid=threadIdx.x;
  red[tid]=val; __syncthreads();
  for (int st=128; st>0; st>>=1){ if (tid<st) red[tid]=fmaxf(red[tid],red[tid+st]); __syncthreads(); }
  float mx=red[0]; __syncthreads();
  float ex=__expf(val-mx); red[tid]=ex; __syncthreads();
  for (int st=128; st>0; st>>=1){ if (tid<st) red[tid]+=red[tid+st]; __syncthreads(); }
  float inv=1.f/red[0];
  p[tid]=ex*inv; __syncthreads();
}

// ---------------- additive-style attention (ptc: +1, ptm: -1), bf16 out ----------------
__global__ __launch_bounds__(256) void k_attn_add(const float* __restrict__ A, const float* __restrict__ Bq,
                          const float* __restrict__ v, float sign,
                          const float* __restrict__ V, unsigned short* __restrict__ aggout, int off){
  __shared__ __align__(16) float bq[EE];
  __shared__ __align__(16) float vv[EE];
  __shared__ float p[SS]; __shared__ float red[SS];
  int q=blockIdx.x, b=blockIdx.y, tid=threadIdx.x;
  if (tid<EE){ bq[tid]=sign*Bq[((size_t)b*SS+q)*EE+tid]; vv[tid]=v[tid]; }
  __syncthreads();
  const float* Ar = A + ((size_t)b*SS+tid)*EE;
  float s=0.f;
  #pragma unroll
  for (int e=0;e<EE;e+=4){
    float4 a=*(const float4*)(Ar+e);
    float4 bb=*(const float4*)(bq+e);
    float4 vw=*(const float4*)(vv+e);
    s += vw.x*tanh_fast(a.x+bb.x)+vw.y*tanh_fast(a.y+bb.y)+vw.z*tanh_fast(a.z+bb.z)+vw.w*tanh_fast(a.w+bb.w);
  }
  softmax256(s, red, p);
  const float* V0 = V + (size_t)b*SS*D2;
  float o=0.f;
  for (int k=0;k<SS;k++) o += p[k]*V0[(size_t)k*D2+tid];
  aggout[((size_t)b*SS+q)*D12 + off + tid] = (unsigned short)bf16_rne(o);
}

// ---------------- bilinear attention (ptb), bf16 out ----------------
__global__ __launch_bounds__(256) void k_attn_bil(const float* __restrict__ Pb, const float* __restrict__ hq,
                          const float* __restrict__ V, unsigned short* __restrict__ aggout, int off){
  __shared__ __align__(16) float hqq[D2];
  __shared__ float p[SS]; __shared__ float red[SS];
  int q=blockIdx.x, b=blockIdx.y, tid=threadIdx.x;
  hqq[tid]=hq[((size_t)b*SS+q)*D2+tid];
  __syncthreads();
  const float* Pr = Pb + ((size_t)b*SS+tid)*D2;
  float s=0.f;
  #pragma unroll
  for (int d=0;d<D2;d+=4){
    float4 a=*(const float4*)(Pr+d);
    float4 hh=*(const float4*)(hqq+d);
    s += a.x*hh.x+a.y*hh.y+a.z*hh.z+a.w*hh.w;
  }
  softmax256(s, red, p);
  const float* V0 = V + (size_t)b*SS*D2;
  float o=0.f;
  for (int k=0;k<SS;k++) o += p[k]*V0[(size_t)k*D2+tid];
  aggout[((size_t)b*SS+q)*D12 + off + tid] = (unsigned short)bf16_rne(o);
}

// ------- fused ptd/pts: MFMA scores + tanh/v reduce + softmax + PV, bf16 out -------
__global__ __launch_bounds__(256, 2) void k_mulattn_fused(
    const unsigned short* __restrict__ keysb,
    const float* __restrict__ qm,
    const unsigned short* __restrict__ Wb,
    const float* __restrict__ v,
    const float* __restrict__ V,
    unsigned short* __restrict__ aggout, int off){
  __shared__ __align__(16) float qrow[D2];
  __shared__ __align__(16) float vrow[EE];
  __shared__ float scq[SS];
  __shared__ float red[SS];
  __shared__ float p[SS];
  int q=blockIdx.x, b=blockIdx.y, tid=threadIdx.x;
  int wave=tid>>6, lane=tid&63;
  size_t bS = (size_t)b*SS;
  qrow[tid]=qm[(bS+q)*D2+tid];
  if (tid<EE) vrow[tid]=v[tid];
  __syncthreads();

  f32x16 acc[2][4]={};
  int m0 = wave*64;
  int col = lane&31, half = lane>>5;
  const unsigned short* krow0 = keysb + (bS + m0 + col)*D2 + half*8;
  const unsigned short* krow1 = krow0 + 32*D2;
  const unsigned short* wrow[4];
  #pragma unroll
  for (int n=0;n<4;n++) wrow[n] = Wb + (size_t)(n*32+col)*D2 + half*8;

  for (int d0=0; d0<D2; d0+=16){
    float4 qsA = *(const float4*)&qrow[d0 + half*8];
    float4 qsB = *(const float4*)&qrow[d0 + half*8 + 4];
    short8 bfrag[4];
    #pragma unroll
    for (int n=0;n<4;n++) bfrag[n] = __builtin_bit_cast(short8, *(const uint4*)(wrow[n]+d0));
    #pragma unroll
    for (int i=0;i<2;i++){
      uint4 raw = *(const uint4*)((i? krow1:krow0) + d0);
      float f0=bf16_to_f(raw.x)*qsA.x, f1=bf16hi_to_f(raw.x)*qsA.y;
      float f2=bf16_to_f(raw.y)*qsA.z, f3=bf16hi_to_f(raw.y)*qsA.w;
      float f4=bf16_to_f(raw.z)*qsB.x, f5=bf16hi_to_f(raw.z)*qsB.y;
      float f6=bf16_to_f(raw.w)*qsB.z, f7=bf16hi_to_f(raw.w)*qsB.w;
      uint4 pk;
      pk.x=pack_bf16x2(f0,f1);
      pk.y=pack_bf16x2(f2,f3);
      pk.z=pack_bf16x2(f4,f5);
      pk.w=pack_bf16x2(f6,f7);
      short8 afrag = __builtin_bit_cast(short8, pk);
      #pragma unroll
      for (int n=0;n<4;n++)
        acc[i][n] = __builtin_amdgcn_mfma_f32_32x32x16_bf16(afrag, bfrag[n], acc[i][n], 0,0,0);
    }
  }
  float vn[4];
  #pragma unroll
  for (int n=0;n<4;n++) vn[n]=vrow[n*32+col];
  #pragma unroll
  for (int i=0;i<2;i++){
    #pragma unroll
    for (int r=0;r<16;r++){
      float s = vn[0]*tanh_fast(acc[i][0][r]) + vn[1]*tanh_fast(acc[i][1][r])
              + vn[2]*tanh_fast(acc[i][2][r]) + vn[3]*tanh_fast(acc[i][3][r]);
      s += __shfl_xor(s,1,32); s += __shfl_xor(s,2,32); s += __shfl_xor(s,4,32);
      s += __shfl_xor(s,8,32); s += __shfl_xor(s,16,32);
      int k = m0 + i*32 + (r&3) + 8*(r>>2) + 4*half;
      scq[k] = s;
    }
  }
  __syncthreads();
  float val = scq[tid];
  softmax256(val, red, p);
  const float* V0 = V + bS*D2;
  float o=0.f;
  for (int k=0;k<SS;k++) o += p[k]*V0[(size_t)k*D2+tid];
  aggout[(bS+q)*D12 + off + tid] = (unsigned short)bf16_rne(o);
}

// ---------------- rl pooling over hq + folded sB = rl @ Wc2^T ----------------
__global__ __launch_bounds__(256) void k_rl(const float* __restrict__ spj, const float* __restrict__ hq,
                    const float* __restrict__ vp, const float* __restrict__ Wc2,
                    float* __restrict__ sB){
  __shared__ __align__(16) float vpl[EE];
  __shared__ float p[SS]; __shared__ float red[SS];
  __shared__ __align__(16) float rr[D2];
  int b=blockIdx.x, tid=threadIdx.x;
  if (tid<EE) vpl[tid]=vp[tid];
  __syncthreads();
  const float* row = spj + ((size_t)b*SS+tid)*EE;
  float sj=0.f;
  #pragma unroll
  for (int e=0;e<EE;e+=4){
    float4 a=*(const float4*)(row+e);
    float4 vw=*(const float4*)(vpl+e);
    sj += vw.x*tanh_fast(a.x)+vw.y*tanh_fast(a.y)+vw.z*tanh_fast(a.z)+vw.w*tanh_fast(a.w);
  }
  softmax256(sj, red, p);
  float o=0.f;
  for (int s=0;s<SS;s++) o += p[s]*hq[((size_t)b*SS+s)*D2+tid];
  rr[tid]=o; __syncthreads();
  if (tid<EE){
    const float* wr = Wc2 + (size_t)tid*D2;
    float a=0.f;
    #pragma unroll
    for (int d=0;d<D2;d+=4){
      float4 w4=*(const float4*)(wr+d);
      float4 r4=*(const float4*)(rr+d);
      a += w4.x*r4.x+w4.y*r4.y+w4.z*r4.z+w4.w*r4.w;
    }
    sB[(size_t)b*EE+tid]=a;
  }
}

// ---------------- final pooling + prediction ----------------
__global__ __launch_bounds__(256) void k_final(const float* __restrict__ sA, const float* __restrict__ sB,
                       const float* __restrict__ vc, const float* __restrict__ agg_rep,
                       const float* __restrict__ Wpred, float* __restrict__ out){
  __shared__ __align__(16) float sBl[EE];
  __shared__ __align__(16) float vcl[EE];
  __shared__ float p[SS]; __shared__ float red[SS]; __shared__ float rr[D2];
  int b=blockIdx.x, tid=threadIdx.x;
  if (tid<EE){ sBl[tid]=sB[(size_t)b*EE+tid]; vcl[tid]=vc[tid]; }
  __syncthreads();
  const float* rowA = sA + ((size_t)b*SS+tid)*EE;
  float sc=0.f;
  #pragma unroll
  for (int e=0;e<EE;e+=4){
    float4 a=*(const float4*)(rowA+e);
    float4 bb=*(const float4*)(sBl+e);
    float4 vw=*(const float4*)(vcl+e);
    sc += vw.x*(a.x+bb.x)+vw.y*(a.y+bb.y)+vw.z*(a.z+bb.z)+vw.w*(a.w+bb.w);
  }
  softmax256(sc, red, p);
  float o=0.f;
  for (int s=0;s<SS;s++) o += p[s]*agg_rep[((size_t)b*SS+s)*D2+tid];
  rr[tid]=o; __syncthreads();
  if (tid<LL){
    float a=0.f;
    const float* wr = Wpred + (size_t)tid*D2;
    for (int d=0;d<D2;d++) a += wr[d]*rr[d];
    out[(size_t)b*LL+tid]=sigmoidf_(a);
  }
}

extern "C" void kernel_launch(void* const* d_in, const int* in_sizes, int n_in,
                              void* d_out, int out_size, void* d_ws, size_t ws_size,
                              hipStream_t stream){
  (void)in_sizes; (void)n_in; (void)out_size; (void)ws_size;
  const int*   inp = (const int*)d_in[0];
  const float* emb = (const float*)d_in[1];
  const float* enc_wih_f=(const float*)d_in[2],  *enc_whh_f=(const float*)d_in[3],
             *enc_bih_f=(const float*)d_in[4],  *enc_bhh_f=(const float*)d_in[5];
  const float* enc_wih_b=(const float*)d_in[6],  *enc_whh_b=(const float*)d_in[7],
             *enc_bih_b=(const float*)d_in[8],  *enc_bhh_b=(const float*)d_in[9];
  const float* hid_wih_f=(const float*)d_in[10], *hid_whh_f=(const float*)d_in[11],
             *hid_bih_f=(const float*)d_in[12], *hid_bhh_f=(const float*)d_in[13];
  const float* hid_wih_b=(const float*)d_in[14], *hid_whh_b=(const float*)d_in[15],
             *hid_bih_b=(const float*)d_in[16], *hid_bhh_b=(const float*)d_in[17];
  const float* agg_wih_f=(const float*)d_in[18], *agg_whh_f=(const float*)d_in[19],
             *agg_bih_f=(const float*)d_in[20], *agg_bhh_f=(const float*)d_in[21];
  const float* agg_wih_b=(const float*)d_in[22], *agg_whh_b=(const float*)d_in[23],
             *agg_bih_b=(const float*)d_in[24], *agg_bhh_b=(const float*)d_in[25];
  const float* Wc1=(const float*)d_in[26], *Wc2=(const float*)d_in[27], *vc=(const float*)d_in[28];
  const float* Wb =(const float*)d_in[29];
  const float* Wd =(const float*)d_in[30], *vd=(const float*)d_in[31];
  const float* Wm =(const float*)d_in[32], *vm=(const float*)d_in[33];
  const float* Ws =(const float*)d_in[34], *vs=(const float*)d_in[35];
  const float* Wp =(const float*)d_in[36], *vp=(const float*)d_in[37];
  const float* Wpred=(const float*)d_in[38];

  float* ws = (float*)d_ws;
  size_t o = 0;
  float* gxf     = ws + o; o += (size_t)BB*SS*H3;
  float* gxb     = ws + o; o += (size_t)BB*SS*H3;
  float* hp      = ws + o; o += (size_t)BB*SS*D2;
  float* hq      = ws + o; o += (size_t)BB*SS*D2;
  float* hidden  = ws + o; o += (size_t)2*BB*EE;
  float* s1      = ws + o; o += (size_t)BB*SS*EE;
  float* s2      = ws + o; o += (size_t)BB*SS*EE;
  float* Am      = ws + o; o += (size_t)BB*SS*EE;
  float* Bm      = ws + o; o += (size_t)BB*SS*EE;
  float* Pb      = ws + o; o += (size_t)BB*SS*D2;
  float* spj     = ws + o; o += (size_t)BB*SS*EE;
  float* agg_rep = ws + o; o += (size_t)BB*SS*D2;
  float* sA      = ws + o; o += (size_t)BB*SS*EE;
  float* sB      = ws + o; o += (size_t)BB*EE;
  // bf16 buffers (ushort counts, all even -> advance o by count/2)
  unsigned short* x_bf      = (unsigned short*)(ws+o); o += (size_t)BB*SS*DP/2;
  unsigned short* hp_bf     = (unsigned short*)(ws+o); o += (size_t)BB*SS*D2/2;
  unsigned short* hq_bf     = (unsigned short*)(ws+o); o += (size_t)BB*SS*D2/2;
  unsigned short* agg_bf    = (unsigned short*)(ws+o); o += (size_t)BB*SS*D12/2;
  unsigned short* aggrep_bf = (unsigned short*)(ws+o); o += (size_t)BB*SS*D2/2;
  unsigned short* encf_bf   = (unsigned short*)(ws+o); o += (size_t)H3*DP/2;
  unsigned short* encb_bf   = (unsigned short*)(ws+o); o += (size_t)H3*DP/2;
  unsigned short* hidf_bf   = (unsigned short*)(ws+o); o += (size_t)H3*D2/2;
  unsigned short* hidb_bf   = (unsigned short*)(ws+o); o += (size_t)H3*D2/2;
  unsigned short* aggf_bf   = (unsigned short*)(ws+o); o += (size_t)H3*D12/2;
  unsigned short* aggb_bf   = (unsigned short*)(ws+o); o += (size_t)H3*D12/2;
  unsigned short* Wc1_bf    = (unsigned short*)(ws+o); o += (size_t)EE*D2/2;
  unsigned short* Wc2_bf    = (unsigned short*)(ws+o); o += (size_t)EE*D2/2;
  unsigned short* Wm_bf     = (unsigned short*)(ws+o); o += (size_t)EE*D2/2;
  unsigned short* Wb_bf     = (unsigned short*)(ws+o); o += (size_t)D2*D2/2;
  unsigned short* Wp_bf     = (unsigned short*)(ws+o); o += (size_t)EE*D2/2;
  unsigned short* Wd_bf     = (unsigned short*)(ws+o); o += (size_t)EE*D2/2;
  unsigned short* Ws_bf     = (unsigned short*)(ws+o); o += (size_t)EE*D2/2;

  const int M = BB*SS; // 1024
  auto mmbf=[&](const unsigned short* X,const unsigned short* W,const float* bias,
                float* outp,int N,int K,int z,int kspan){
    dim3 g(N/32, M/64, z);
    k_mmbf<<<g,64,0,stream>>>(X,W,bias,outp,N,K,kspan);
  };

  // ---- input prep ----
  k_embed<<<M,256,0,stream>>>(inp, emb, x_bf);
  CvtArgs ca;
  ca.s[0]  = {enc_wih_f, encf_bf, H3, DD, DP};
  ca.s[1]  = {enc_wih_b, encb_bf, H3, DD, DP};
  ca.s[2]  = {hid_wih_f, hidf_bf, H3, D2, D2};
  ca.s[3]  = {hid_wih_b, hidb_bf, H3, D2, D2};
  ca.s[4]  = {agg_wih_f, aggf_bf, H3, D12, D12};
  ca.s[5]  = {agg_wih_b, aggb_bf, H3, D12, D12};
  ca.s[6]  = {Wc1, Wc1_bf, EE, D2, D2};
  ca.s[7]  = {Wc2, Wc2_bf, EE, D2, D2};
  ca.s[8]  = {Wm,  Wm_bf,  EE, D2, D2};
  ca.s[9]  = {Wb,  Wb_bf,  D2, D2, D2};
  ca.s[10] = {Wp,  Wp_bf,  EE, D2, D2};
  ca.s[11] = {Wd,  Wd_bf,  EE, D2, D2};
  ca.s[12] = {Ws,  Ws_bf,  EE, D2, D2};
  {
    int maxpairs = H3*D12/2;  // 294912
    dim3 g((maxpairs+255)/256, 13);
    k_cvt_weights<<<g,256,0,stream>>>(ca);
  }

  // ---- encoder BiGRU (fused bf16 out) ----
  k_init2<<<M,H3,0,stream>>>(gxf, enc_bih_f, gxb, enc_bih_b);
  mmbf(x_bf, encf_bf, nullptr, gxf, H3, DP, 4, 80);
  mmbf(x_bf, encb_bf, nullptr, gxb, H3, DP, 4, 80);
  k_gru_scan<<<dim3(BB,2),512,0,stream>>>(gxf,gxb,enc_whh_f,enc_whh_b,enc_bhh_f,enc_bhh_b,
                                          nullptr,hp,hp_bf,hidden);

  // ---- hidden BiGRU ----
  k_init2<<<M,H3,0,stream>>>(gxf, hid_bih_f, gxb, hid_bih_b);
  mmbf(hp_bf, hidf_bf, nullptr, gxf, H3, D2, 4, 64);
  mmbf(hp_bf, hidb_bf, nullptr, gxb, H3, D2, 4, 64);
  k_gru_scan<<<dim3(BB,2),512,0,stream>>>(gxf,gxb,hid_whh_f,hid_whh_b,hid_bhh_f,hid_bhh_b,
                                          hidden,hq,hq_bf,nullptr);

  // ---- projections (ksplit=1, direct store) ----
  mmbf(hp_bf, Wc1_bf, nullptr, s1,  EE, D2, 1, D2);
  mmbf(hq_bf, Wc2_bf, nullptr, s2,  EE, D2, 1, D2);
  mmbf(hp_bf, Wm_bf,  nullptr, Am,  EE, D2, 1, D2);
  mmbf(hq_bf, Wm_bf,  nullptr, Bm,  EE, D2, 1, D2);
  mmbf(hp_bf, Wb_bf,  nullptr, Pb,  D2, D2, 1, D2);
  mmbf(hq_bf, Wp_bf,  nullptr, spj, EE, D2, 1, D2);

  // ---- attentions -> agg (bf16). slices: hq(0) pts(256) ptc(512) ptd(768) ptb(1024) ptm(1280)
  k_copy_hq<<<M,256,0,stream>>>(hq_bf, agg_bf);
  dim3 gq(SS,BB);
  k_attn_add<<<gq,256,0,stream>>>(s1,s2,vc, 1.f, hp, agg_bf, 512);
  k_attn_add<<<gq,256,0,stream>>>(Am,Bm,vm,-1.f, hp, agg_bf, 1280);
  k_attn_bil<<<gq,256,0,stream>>>(Pb,hq,hp,agg_bf,1024);
  k_mulattn_fused<<<gq,256,0,stream>>>(hp_bf,hq,Wd_bf,vd,hp,agg_bf,768);
  k_mulattn_fused<<<gq,256,0,stream>>>(hq_bf,hq,Ws_bf,vs,hq,agg_bf,256);

  // ---- aggregation BiGRU ----
  k_init2<<<M,H3,0,stream>>>(gxf, agg_bih_f, gxb, agg_bih_b);
  mmbf(agg_bf, aggf_bf, nullptr, gxf, H3, D12, 8, 192);
  mmbf(agg_bf, aggb_bf, nullptr, gxb, H3, D12, 8, 192);
  k_gru_scan<<<dim3(BB,2),512,0,stream>>>(gxf,gxb,agg_whh_f,agg_whh_b,agg_bhh_f,agg_bhh_b,
                                          nullptr,agg_rep,aggrep_bf,nullptr);

  // ---- pooling + prediction ----
  k_rl<<<BB,256,0,stream>>>(spj,hq,vp,Wc2,sB);
  mmbf(aggrep_bf, Wc1_bf, nullptr, sA, EE, D2, 1, D2);
  k_final<<<BB,256,0,stream>>>(sA,sB,vc,agg_rep,Wpred,(float*)d_out);
}

// Round 7
// 1105.957 us; speedup vs baseline: 1.5107x; 1.0179x over previous
//
#include <hip/hip_runtime.h>
#include <math.h>

#define BB 4
#define SS 256
#define DD 300
#define DP 304   // DD padded to multiple of 16
#define EE 128
#define LL 20
#define H3 384
#define D2 256   // 2E
#define D12 1536 // 12E

typedef __attribute__((ext_vector_type(8)))  short short8;
typedef __attribute__((ext_vector_type(16))) float f32x16;
typedef __attribute__((ext_vector_type(2)))  float f32x2;

__device__ __forceinline__ float tanh_fast(float x){
  float e = __expf(2.f*x);
  return 1.f - 2.f/(e+1.f);
}
__device__ __forceinline__ float sigmoidf_(float x){ return 1.f/(1.f+__expf(-x)); }
__device__ __forceinline__ float bf16_to_f(unsigned u){ return __builtin_bit_cast(float, u<<16); }
__device__ __forceinline__ float bf16hi_to_f(unsigned u){ return __builtin_bit_cast(float, u & 0xFFFF0000u); }
__device__ __forceinline__ unsigned bf16_rne(float f){
  unsigned u = __builtin_bit_cast(unsigned, f);
  return (u + 0x7FFFu + ((u>>16)&1u)) >> 16;
}
__device__ __forceinline__ unsigned pack_bf16x2(float lo, float hi){
  return bf16_rne(lo) | (bf16_rne(hi)<<16);
}

__device__ __forceinline__ float wred_max(float v){
  #pragma unroll
  for (int st=1; st<64; st<<=1) v = fmaxf(v, __shfl_xor(v, st));
  return v;
}
__device__ __forceinline__ float wred_sum(float v){
  #pragma unroll
  for (int st=1; st<64; st<<=1) v += __shfl_xor(v, st);
  return v;
}

// --------- block softmax over 256 values, wave-reduce based (3 barriers) ---------
__device__ __forceinline__ void softmax256f(float val, float* red, float* p){
  int tid=threadIdx.x, wv=tid>>6;
  float m = wred_max(val);
  if ((tid&63)==0) red[wv]=m;
  __syncthreads();
  float mx = fmaxf(fmaxf(red[0],red[1]),fmaxf(red[2],red[3]));
  float ex = __expf(val-mx);
  float s = wred_sum(ex);
  if ((tid&63)==0) red[8+wv]=s;
  __syncthreads();
  float inv = 1.f/(red[8]+red[9]+red[10]+red[11]);
  p[tid]=ex*inv;
  __syncthreads();
}

// ---------------- fused weight conversion (14 segments, K-padding aware) ----------------
struct CvtSeg { const float* src; unsigned short* dst; int rows, Ks, Kd; };
struct CvtArgs { CvtSeg s[14]; };
__global__ void k_cvt_weights(CvtArgs a){
  CvtSeg sg = a.s[blockIdx.y];
  int p = blockIdx.x*256 + threadIdx.x;          // dst pair index
  int Kd2 = sg.Kd>>1;
  int npairs = sg.rows*Kd2;
  if (p >= npairs) return;
  int row = p/Kd2, kk = (p - row*Kd2)*2;
  float f0 = (kk   < sg.Ks)? sg.src[(size_t)row*sg.Ks+kk  ] : 0.f;
  float f1 = (kk+1 < sg.Ks)? sg.src[(size_t)row*sg.Ks+kk+1] : 0.f;
  *(unsigned*)(sg.dst + (size_t)row*sg.Kd + kk) = pack_bf16x2(f0,f1);
}

// ---------------- embedding gather -> padded bf16 ----------------
__global__ void k_embed(const int* __restrict__ inp, const float* __restrict__ emb,
                        unsigned short* __restrict__ xb){
  int row = blockIdx.x;            // b*S+s
  int idx = inp[row];
  const float* src = emb + (size_t)idx*DD;
  unsigned short* dst = xb + (size_t)row*DP;
  int p = threadIdx.x;             // pair index, 152 pairs
  if (p < DP/2){
    float f0 = (2*p   < DD)? src[2*p  ] : 0.f;
    float f1 = (2*p+1 < DD)? src[2*p+1] : 0.f;
    *(unsigned*)(dst + 2*p) = pack_bf16x2(f0,f1);
  }
}

// ---------------- bf16 MFMA matmul: out[M,N] (+)= X[M,K] @ W[N,K]^T ----------------
// z==1: plain store + bias (used everywhere now — no atomics, no init pass).
__global__ __launch_bounds__(64) void k_mmbf(
    const unsigned short* __restrict__ X, const unsigned short* __restrict__ W,
    const float* __restrict__ bias, float* __restrict__ out,
    int N, int K, int kspan){
  int lane=threadIdx.x, col=lane&31, half=lane>>5;
  int n0=blockIdx.x*32, m0=blockIdx.y*64;
  int ks=blockIdx.z*kspan, ke=ks+kspan; if (ke>K) ke=K;
  const unsigned short* pa0 = X + (size_t)(m0+col)*K + half*8;
  const unsigned short* pa1 = pa0 + (size_t)32*K;
  const unsigned short* pb  = W + (size_t)(n0+col)*K + half*8;
  f32x16 acc0={}, acc1={};
  #pragma unroll 2
  for (int k=ks;k<ke;k+=16){
    short8 a0=__builtin_bit_cast(short8, *(const uint4*)(pa0+k));
    short8 a1=__builtin_bit_cast(short8, *(const uint4*)(pa1+k));
    short8 bv=__builtin_bit_cast(short8, *(const uint4*)(pb +k));
    acc0=__builtin_amdgcn_mfma_f32_32x32x16_bf16(a0,bv,acc0,0,0,0);
    acc1=__builtin_amdgcn_mfma_f32_32x32x16_bf16(a1,bv,acc1,0,0,0);
  }
  int cn = n0+col;
  if (gridDim.z==1){
    float bn = bias? bias[cn] : 0.f;
    #pragma unroll
    for (int r=0;r<16;r++){
      int row=(r&3)+8*(r>>2)+4*half;
      out[(size_t)(m0+row)*N+cn]    = acc0[r]+bn;
      out[(size_t)(m0+32+row)*N+cn] = acc1[r]+bn;
    }
  } else {
    #pragma unroll
    for (int r=0;r<16;r++){
      int row=(r&3)+8*(r>>2)+4*half;
      atomicAdd(&out[(size_t)(m0+row)*N+cn],    acc0[r]);
      atomicAdd(&out[(size_t)(m0+32+row)*N+cn], acc1[r]);
    }
  }
}

// ---------------- GRU scan (one block per (batch, direction)) ----------------
// Round-6-proven structure (188us, 0 bank conflicts): 512 threads = 8 waves,
// readlane h-broadcast (VALU pipes), stride-9 conflict-free partials,
// depth-2 gx prefetch, fused bf16 store. Round-7: optional second bf16
// output (agg slice, stride D12) folds k_copy_hq into the hidden scan.
#define GW 8          // dot waves
#define CH 16         // h-chunk per wave = 128/GW
#define PSTR 9        // partial row stride (floats), coprime with 32

__global__ __launch_bounds__(512, 1) void k_gru_scan(
                          const float* __restrict__ gxf, const float* __restrict__ gxb,
                          const float* __restrict__ whhf, const float* __restrict__ whhb,
                          const float* __restrict__ bhhf, const float* __restrict__ bhhb,
                          const float* __restrict__ h0,
                          float* __restrict__ out,
                          unsigned short* __restrict__ out_bf,
                          unsigned short* __restrict__ out_bf2,
                          float* __restrict__ hT){
  int b=blockIdx.x, dir=blockIdx.y, tid=threadIdx.x;
  const float* gx  = dir? gxb : gxf;
  const float* whh = dir? whhb : whhf;
  const float* bhh = dir? bhhb : bhhf;
  int w = tid>>6, lane = tid&63;
  int chunk = w*CH;

  // weights: rows lane+64*(2p), lane+64*(2p+1), chunk slice, packed pairs
  f32x2 wv[3][CH];
  #pragma unroll
  for (int p=0;p<3;p++){
    const float* r0 = whh + (size_t)(lane+64*(2*p  ))*EE + chunk;
    const float* r1 = whh + (size_t)(lane+64*(2*p+1))*EE + chunk;
    #pragma unroll
    for (int k=0;k<CH;k++){ wv[p][k].x = r0[k]; wv[p][k].y = r1[k]; }
  }

  __shared__ __align__(16) float hsh[EE];
  __shared__ float part[H3*PSTR];

  bool comb = (tid < EE);
  float hprev=0.f, b_r=0.f, b_z=0.f, b_n=0.f;
  float xrA=0.f,xzA=0.f,xnA=0.f, xrB=0.f,xzB=0.f,xnB=0.f;
  if (comb){
    int r = tid;
    b_r = bhh[r]; b_z = bhh[r+EE]; b_n = bhh[r+2*EE];
    hprev = h0? h0[((size_t)dir*BB+b)*EE + r] : 0.f;
    hsh[r] = hprev;
    int s0 = dir? (SS-1) : 0;
    int s1 = dir? (SS-2) : 1;
    const float* g0 = gx + ((size_t)b*SS+s0)*H3;
    const float* g1 = gx + ((size_t)b*SS+s1)*H3;
    xrA=g0[r]; xzA=g0[r+EE]; xnA=g0[r+2*EE];
    xrB=g1[r]; xzB=g1[r+EE]; xnB=g1[r+2*EE];
  }
  __syncthreads();

  auto dotphase = [&](){
    float vh = hsh[chunk + (lane & (CH-1))];   // 1 conflict-free ds_read_b32/wave
    f32x2 acc0={0.f,0.f}, acc1={0.f,0.f}, acc2={0.f,0.f};
    #pragma unroll
    for (int k=0;k<CH;k++){
      float s = __builtin_bit_cast(float,
                  __builtin_amdgcn_readlane(__builtin_bit_cast(int, vh), k));
      acc0 += wv[0][k]*s;
      acc1 += wv[1][k]*s;
      acc2 += wv[2][k]*s;
    }
    part[(lane      )*PSTR + w] = acc0.x;
    part[(lane+ 64  )*PSTR + w] = acc0.y;
    part[(lane+128  )*PSTR + w] = acc1.x;
    part[(lane+192  )*PSTR + w] = acc1.y;
    part[(lane+256  )*PSTR + w] = acc2.x;
    part[(lane+320  )*PSTR + w] = acc2.y;
  };

  auto combphase = [&](int t, float xr, float xz, float xn,
                       float& pxr, float& pxz, float& pxn){
    int r = tid;
    float ar=0.f, az=0.f, an=0.f;
    #pragma unroll
    for (int c=0;c<GW;c++){
      ar += part[(r      )*PSTR+c];
      az += part[(r+128  )*PSTR+c];
      an += part[(r+256  )*PSTR+c];
    }
    int s = dir? (SS-1-t) : t;
    float rg = sigmoidf_(xr + ar + b_r);
    float zg = sigmoidf_(xz + az + b_z);
    float ng = tanh_fast(xn + rg*(an + b_n));
    float h2 = (1.f-zg)*ng + zg*hprev;
    hprev = h2;
    hsh[r] = h2;
    size_t rowi = (size_t)b*SS+s;
    size_t oi = rowi*D2 + (size_t)dir*EE + r;
    out[oi] = h2;
    unsigned short hb = (unsigned short)bf16_rne(h2);
    if (out_bf)  out_bf[oi] = hb;
    if (out_bf2) out_bf2[rowi*D12 + (size_t)dir*EE + r] = hb;
    // depth-2 prefetch: reload this set for t+2 (consumed 2 steps from now)
    if (t+2 < SS){
      int sn = dir? (SS-3-t) : (t+2);
      const float* gn = gx + ((size_t)b*SS+sn)*H3;
      pxr=gn[r]; pxz=gn[r+EE]; pxn=gn[r+2*EE];
    }
  };

  for (int t=0;t<SS;t+=2){
    dotphase();
    __syncthreads();
    if (comb) combphase(t, xrA,xzA,xnA, xrA,xzA,xnA);
    __syncthreads();
    dotphase();
    __syncthreads();
    if (comb) combphase(t+1, xrB,xzB,xnB, xrB,xzB,xnB);
    __syncthreads();
  }
  if (hT && comb) hT[((size_t)dir*BB+b)*EE+tid]=hprev;
}

// ------- fused cheap attentions ptc/ptm/ptb: shared PV over hp, bf16 out -------
// s1Am: [M][256] = [s1 | Am] (hp @ [Wc1|Wm]^T), s2BS: [M][384] = [s2 | Bm | spj].
__global__ __launch_bounds__(256) void k_attn3(
    const float* __restrict__ s1Am, const float* __restrict__ s2BS,
    const float* __restrict__ Pb, const float* __restrict__ hq,
    const float* __restrict__ vc, const float* __restrict__ vm,
    const float* __restrict__ V, unsigned short* __restrict__ aggout){
  __shared__ __align__(16) float bq[EE];
  __shared__ __align__(16) float bm[EE];
  __shared__ __align__(16) float vvc[EE];
  __shared__ __align__(16) float vvm[EE];
  __shared__ __align__(16) float hqq[D2];
  __shared__ float pc[SS]; __shared__ float pm[SS]; __shared__ float pbl[SS];
  __shared__ float red[32];
  int q=blockIdx.x, b=blockIdx.y, tid=threadIdx.x;
  size_t bS=(size_t)b*SS;
  if (tid<EE){
    const float* qrow = s2BS + (bS+q)*384;
    bq[tid]=qrow[tid]; bm[tid]=qrow[EE+tid];
    vvc[tid]=vc[tid];  vvm[tid]=vm[tid];
  }
  hqq[tid]=hq[(bS+q)*D2+tid];
  __syncthreads();

  const float* kr = s1Am + (bS+tid)*(size_t)256;
  float sc=0.f, sm=0.f;
  #pragma unroll
  for (int e=0;e<EE;e+=4){
    float4 a1=*(const float4*)(kr+e);
    float4 am=*(const float4*)(kr+EE+e);
    float4 b1=*(const float4*)(bq+e);
    float4 b2=*(const float4*)(bm+e);
    float4 wc=*(const float4*)(vvc+e);
    float4 wm=*(const float4*)(vvm+e);
    sc += wc.x*tanh_fast(a1.x+b1.x)+wc.y*tanh_fast(a1.y+b1.y)
        + wc.z*tanh_fast(a1.z+b1.z)+wc.w*tanh_fast(a1.w+b1.w);
    sm += wm.x*tanh_fast(am.x-b2.x)+wm.y*tanh_fast(am.y-b2.y)
        + wm.z*tanh_fast(am.z-b2.z)+wm.w*tanh_fast(am.w-b2.w);
  }
  float sb=0.f;
  const float* Pr = Pb + (bS+tid)*(size_t)D2;
  #pragma unroll
  for (int d=0;d<D2;d+=4){
    float4 a=*(const float4*)(Pr+d);
    float4 hh=*(const float4*)(hqq+d);
    sb += a.x*hh.x+a.y*hh.y+a.z*hh.z+a.w*hh.w;
  }

  // fused triple softmax (3 barriers)
  int wvid=tid>>6;
  float m1=wred_max(sc), m2=wred_max(sm), m3=wred_max(sb);
  if ((tid&63)==0){ red[wvid]=m1; red[4+wvid]=m2; red[8+wvid]=m3; }
  __syncthreads();
  m1=fmaxf(fmaxf(red[0],red[1]),fmaxf(red[2],red[3]));
  m2=fmaxf(fmaxf(red[4],red[5]),fmaxf(red[6],red[7]));
  m3=fmaxf(fmaxf(red[8],red[9]),fmaxf(red[10],red[11]));
  float e1=__expf(sc-m1), e2=__expf(sm-m2), e3=__expf(sb-m3);
  float t1=wred_sum(e1), t2=wred_sum(e2), t3=wred_sum(e3);
  if ((tid&63)==0){ red[16+wvid]=t1; red[20+wvid]=t2; red[24+wvid]=t3; }
  __syncthreads();
  pc[tid] =e1/(red[16]+red[17]+red[18]+red[19]);
  pm[tid] =e2/(red[20]+red[21]+red[22]+red[23]);
  pbl[tid]=e3/(red[24]+red[25]+red[26]+red[27]);
  __syncthreads();

  // shared PV: one V load feeds 3 accumulators
  const float* V0 = V + bS*D2;
  float oc=0.f, om=0.f, ob=0.f;
  for (int k=0;k<SS;k++){
    float v=V0[(size_t)k*D2+tid];
    oc+=pc[k]*v; om+=pm[k]*v; ob+=pbl[k]*v;
  }
  unsigned short* ao = aggout + (bS+q)*(size_t)D12;
  ao[512 +tid]=(unsigned short)bf16_rne(oc);
  ao[1280+tid]=(unsigned short)bf16_rne(om);
  ao[1024+tid]=(unsigned short)bf16_rne(ob);
}

// ------- fused ptd/pts: MFMA scores + tanh/v reduce + softmax + PV, bf16 out -------
__global__ __launch_bounds__(256, 2) void k_mulattn_fused(
    const unsigned short* __restrict__ keysb,
    const float* __restrict__ qm,
    const unsigned short* __restrict__ Wb,
    const float* __restrict__ v,
    const float* __restrict__ V,
    unsigned short* __restrict__ aggout, int off){
  __shared__ __align__(16) float qrow[D2];
  __shared__ __align__(16) float vrow[EE];
  __shared__ float scq[SS];
  __shared__ float red[16];
  __shared__ float p[SS];
  int q=blockIdx.x, b=blockIdx.y, tid=threadIdx.x;
  int wave=tid>>6, lane=tid&63;
  size_t bS = (size_t)b*SS;
  qrow[tid]=qm[(bS+q)*D2+tid];
  if (tid<EE) vrow[tid]=v[tid];
  __syncthreads();

  f32x16 acc[2][4]={};
  int m0 = wave*64;
  int col = lane&31, half = lane>>5;
  const unsigned short* krow0 = keysb + (bS + m0 + col)*D2 + half*8;
  const unsigned short* krow1 = krow0 + 32*D2;
  const unsigned short* wrow[4];
  #pragma unroll
  for (int n=0;n<4;n++) wrow[n] = Wb + (size_t)(n*32+col)*D2 + half*8;

  for (int d0=0; d0<D2; d0+=16){
    float4 qsA = *(const float4*)&qrow[d0 + half*8];
    float4 qsB = *(const float4*)&qrow[d0 + half*8 + 4];
    short8 bfrag[4];
    #pragma unroll
    for (int n=0;n<4;n++) bfrag[n] = __builtin_bit_cast(short8, *(const uint4*)(wrow[n]+d0));
    #pragma unroll
    for (int i=0;i<2;i++){
      uint4 raw = *(const uint4*)((i? krow1:krow0) + d0);
      float f0=bf16_to_f(raw.x)*qsA.x, f1=bf16hi_to_f(raw.x)*qsA.y;
      float f2=bf16_to_f(raw.y)*qsA.z, f3=bf16hi_to_f(raw.y)*qsA.w;
      float f4=bf16_to_f(raw.z)*qsB.x, f5=bf16hi_to_f(raw.z)*qsB.y;
      float f6=bf16_to_f(raw.w)*qsB.z, f7=bf16hi_to_f(raw.w)*qsB.w;
      uint4 pk;
      pk.x=pack_bf16x2(f0,f1);
      pk.y=pack_bf16x2(f2,f3);
      pk.z=pack_bf16x2(f4,f5);
      pk.w=pack_bf16x2(f6,f7);
      short8 afrag = __builtin_bit_cast(short8, pk);
      #pragma unroll
      for (int n=0;n<4;n++)
        acc[i][n] = __builtin_amdgcn_mfma_f32_32x32x16_bf16(afrag, bfrag[n], acc[i][n], 0,0,0);
    }
  }
  float vn[4];
  #pragma unroll
  for (int n=0;n<4;n++) vn[n]=vrow[n*32+col];
  #pragma unroll
  for (int i=0;i<2;i++){
    #pragma unroll
    for (int r=0;r<16;r++){
      float s = vn[0]*tanh_fast(acc[i][0][r]) + vn[1]*tanh_fast(acc[i][1][r])
              + vn[2]*tanh_fast(acc[i][2][r]) + vn[3]*tanh_fast(acc[i][3][r]);
      s += __shfl_xor(s,1,32); s += __shfl_xor(s,2,32); s += __shfl_xor(s,4,32);
      s += __shfl_xor(s,8,32); s += __shfl_xor(s,16,32);
      int k = m0 + i*32 + (r&3) + 8*(r>>2) + 4*half;
      scq[k] = s;
    }
  }
  __syncthreads();
  float val = scq[tid];
  softmax256f(val, red, p);
  const float* V0 = V + bS*D2;
  float o=0.f;
  for (int k=0;k<SS;k++) o += p[k]*V0[(size_t)k*D2+tid];
  aggout[(bS+q)*D12 + off + tid] = (unsigned short)bf16_rne(o);
}

// ---------------- rl pooling over hq + folded sB = rl @ Wc2^T ----------------
// spj now lives at s2BS[.][256..384)
__global__ __launch_bounds__(256) void k_rl(const float* __restrict__ s2BS, const float* __restrict__ hq,
                    const float* __restrict__ vp, const float* __restrict__ Wc2,
                    float* __restrict__ sB){
  __shared__ __align__(16) float vpl[EE];
  __shared__ float p[SS]; __shared__ float red[16];
  __shared__ __align__(16) float rr[D2];
  int b=blockIdx.x, tid=threadIdx.x;
  if (tid<EE) vpl[tid]=vp[tid];
  __syncthreads();
  const float* row = s2BS + ((size_t)b*SS+tid)*384 + 256;
  float sj=0.f;
  #pragma unroll
  for (int e=0;e<EE;e+=4){
    float4 a=*(const float4*)(row+e);
    float4 vw=*(const float4*)(vpl+e);
    sj += vw.x*tanh_fast(a.x)+vw.y*tanh_fast(a.y)+vw.z*tanh_fast(a.z)+vw.w*tanh_fast(a.w);
  }
  softmax256f(sj, red, p);
  float o=0.f;
  for (int s=0;s<SS;s++) o += p[s]*hq[((size_t)b*SS+s)*D2+tid];
  rr[tid]=o; __syncthreads();
  if (tid<EE){
    const float* wr = Wc2 + (size_t)tid*D2;
    float a=0.f;
    #pragma unroll
    for (int d=0;d<D2;d+=4){
      float4 w4=*(const float4*)(wr+d);
      float4 r4=*(const float4*)(rr+d);
      a += w4.x*r4.x+w4.y*r4.y+w4.z*r4.z+w4.w*r4.w;
    }
    sB[(size_t)b*EE+tid]=a;
  }
}

// ---------------- final pooling + prediction ----------------
__global__ __launch_bounds__(256) void k_final(const float* __restrict__ sA, const float* __restrict__ sB,
                       const float* __restrict__ vc, const float* __restrict__ agg_rep,
                       const float* __restrict__ Wpred, float* __restrict__ out){
  __shared__ __align__(16) float sBl[EE];
  __shared__ __align__(16) float vcl[EE];
  __shared__ float p[SS]; __shared__ float red[16]; __shared__ float rr[D2];
  int b=blockIdx.x, tid=threadIdx.x;
  if (tid<EE){ sBl[tid]=sB[(size_t)b*EE+tid]; vcl[tid]=vc[tid]; }
  __syncthreads();
  const float* rowA = sA + ((size_t)b*SS+tid)*EE;
  float sc=0.f;
  #pragma unroll
  for (int e=0;e<EE;e+=4){
    float4 a=*(const float4*)(rowA+e);
    float4 bb=*(const float4*)(sBl+e);
    float4 vw=*(const float4*)(vcl+e);
    sc += vw.x*(a.x+bb.x)+vw.y*(a.y+bb.y)+vw.z*(a.z+bb.z)+vw.w*(a.w+bb.w);
  }
  softmax256f(sc, red, p);
  float o=0.f;
  for (int s=0;s<SS;s++) o += p[s]*agg_rep[((size_t)b*SS+s)*D2+tid];
  rr[tid]=o; __syncthreads();
  if (tid<LL){
    float a=0.f;
    const float* wr = Wpred + (size_t)tid*D2;
    for (int d=0;d<D2;d++) a += wr[d]*rr[d];
    out[(size_t)b*LL+tid]=sigmoidf_(a);
  }
}

extern "C" void kernel_launch(void* const* d_in, const int* in_sizes, int n_in,
                              void* d_out, int out_size, void* d_ws, size_t ws_size,
                              hipStream_t stream){
  (void)in_sizes; (void)n_in; (void)out_size; (void)ws_size;
  const int*   inp = (const int*)d_in[0];
  const float* emb = (const float*)d_in[1];
  const float* enc_wih_f=(const float*)d_in[2],  *enc_whh_f=(const float*)d_in[3],
             *enc_bih_f=(const float*)d_in[4],  *enc_bhh_f=(const float*)d_in[5];
  const float* enc_wih_b=(const float*)d_in[6],  *enc_whh_b=(const float*)d_in[7],
             *enc_bih_b=(const float*)d_in[8],  *enc_bhh_b=(const float*)d_in[9];
  const float* hid_wih_f=(const float*)d_in[10], *hid_whh_f=(const float*)d_in[11],
             *hid_bih_f=(const float*)d_in[12], *hid_bhh_f=(const float*)d_in[13];
  const float* hid_wih_b=(const float*)d_in[14], *hid_whh_b=(const float*)d_in[15],
             *hid_bih_b=(const float*)d_in[16], *hid_bhh_b=(const float*)d_in[17];
  const float* agg_wih_f=(const float*)d_in[18], *agg_whh_f=(const float*)d_in[19],
             *agg_bih_f=(const float*)d_in[20], *agg_bhh_f=(const float*)d_in[21];
  const float* agg_wih_b=(const float*)d_in[22], *agg_whh_b=(const float*)d_in[23],
             *agg_bih_b=(const float*)d_in[24], *agg_bhh_b=(const float*)d_in[25];
  const float* Wc1=(const float*)d_in[26], *Wc2=(const float*)d_in[27], *vc=(const float*)d_in[28];
  const float* Wb =(const float*)d_in[29];
  const float* Wd =(const float*)d_in[30], *vd=(const float*)d_in[31];
  const float* Wm =(const float*)d_in[32], *vm=(const float*)d_in[33];
  const float* Ws =(const float*)d_in[34], *vs=(const float*)d_in[35];
  const float* Wp =(const float*)d_in[36], *vp=(const float*)d_in[37];
  const float* Wpred=(const float*)d_in[38];

  float* ws = (float*)d_ws;
  size_t o = 0;
  float* gxf     = ws + o; o += (size_t)BB*SS*H3;
  float* gxb     = ws + o; o += (size_t)BB*SS*H3;
  float* hp      = ws + o; o += (size_t)BB*SS*D2;
  float* hq      = ws + o; o += (size_t)BB*SS*D2;
  float* hidden  = ws + o; o += (size_t)2*BB*EE;
  float* s1Am    = ws + o; o += (size_t)BB*SS*256;
  float* s2BS    = ws + o; o += (size_t)BB*SS*384;
  float* Pb      = ws + o; o += (size_t)BB*SS*D2;
  float* agg_rep = ws + o; o += (size_t)BB*SS*D2;
  float* sA      = ws + o; o += (size_t)BB*SS*EE;
  float* sB      = ws + o; o += (size_t)BB*EE;
  // bf16 buffers (ushort counts, all even -> advance o by count/2)
  unsigned short* x_bf      = (unsigned short*)(ws+o); o += (size_t)BB*SS*DP/2;
  unsigned short* hp_bf     = (unsigned short*)(ws+o); o += (size_t)BB*SS*D2/2;
  unsigned short* hq_bf     = (unsigned short*)(ws+o); o += (size_t)BB*SS*D2/2;
  unsigned short* agg_bf    = (unsigned short*)(ws+o); o += (size_t)BB*SS*D12/2;
  unsigned short* aggrep_bf = (unsigned short*)(ws+o); o += (size_t)BB*SS*D2/2;
  unsigned short* encf_bf   = (unsigned short*)(ws+o); o += (size_t)H3*DP/2;
  unsigned short* encb_bf   = (unsigned short*)(ws+o); o += (size_t)H3*DP/2;
  unsigned short* hidf_bf   = (unsigned short*)(ws+o); o += (size_t)H3*D2/2;
  unsigned short* hidb_bf   = (unsigned short*)(ws+o); o += (size_t)H3*D2/2;
  unsigned short* aggf_bf   = (unsigned short*)(ws+o); o += (size_t)H3*D12/2;
  unsigned short* aggb_bf   = (unsigned short*)(ws+o); o += (size_t)H3*D12/2;
  unsigned short* WA_bf     = (unsigned short*)(ws+o); o += (size_t)256*D2/2;  // [Wc1|Wm]
  unsigned short* WB_bf     = (unsigned short*)(ws+o); o += (size_t)384*D2/2;  // [Wc2|Wm|Wp]
  unsigned short* Wb_bf     = (unsigned short*)(ws+o); o += (size_t)D2*D2/2;
  unsigned short* Wd_bf     = (unsigned short*)(ws+o); o += (size_t)EE*D2/2;
  unsigned short* Ws_bf     = (unsigned short*)(ws+o); o += (size_t)EE*D2/2;

  const int M = BB*SS; // 1024
  auto mmbf=[&](const unsigned short* X,const unsigned short* W,const float* bias,
                float* outp,int N,int K){
    dim3 g(N/32, M/64, 1);
    k_mmbf<<<g,64,0,stream>>>(X,W,bias,outp,N,K,K);
  };

  // ---- input prep ----
  k_embed<<<M,256,0,stream>>>(inp, emb, x_bf);
  CvtArgs ca;
  ca.s[0]  = {enc_wih_f, encf_bf, H3, DD, DP};
  ca.s[1]  = {enc_wih_b, encb_bf, H3, DD, DP};
  ca.s[2]  = {hid_wih_f, hidf_bf, H3, D2, D2};
  ca.s[3]  = {hid_wih_b, hidb_bf, H3, D2, D2};
  ca.s[4]  = {agg_wih_f, aggf_bf, H3, D12, D12};
  ca.s[5]  = {agg_wih_b, aggb_bf, H3, D12, D12};
  ca.s[6]  = {Wc1, WA_bf,             EE, D2, D2};
  ca.s[7]  = {Wm,  WA_bf + EE*D2,     EE, D2, D2};
  ca.s[8]  = {Wc2, WB_bf,             EE, D2, D2};
  ca.s[9]  = {Wm,  WB_bf + EE*D2,     EE, D2, D2};
  ca.s[10] = {Wp,  WB_bf + 2*EE*D2,   EE, D2, D2};
  ca.s[11] = {Wb,  Wb_bf, D2, D2, D2};
  ca.s[12] = {Wd,  Wd_bf, EE, D2, D2};
  ca.s[13] = {Ws,  Ws_bf, EE, D2, D2};
  {
    int maxpairs = H3*D12/2;  // 294912
    dim3 g((maxpairs+255)/256, 14);
    k_cvt_weights<<<g,256,0,stream>>>(ca);
  }

  // ---- encoder BiGRU (bias folded into GEMM, no atomics) ----
  mmbf(x_bf, encf_bf, enc_bih_f, gxf, H3, DP);
  mmbf(x_bf, encb_bf, enc_bih_b, gxb, H3, DP);
  k_gru_scan<<<dim3(BB,2),512,0,stream>>>(gxf,gxb,enc_whh_f,enc_whh_b,enc_bhh_f,enc_bhh_b,
                                          nullptr,hp,hp_bf,nullptr,hidden);

  // ---- hidden BiGRU (writes hq slice of agg directly) ----
  mmbf(hp_bf, hidf_bf, hid_bih_f, gxf, H3, D2);
  mmbf(hp_bf, hidb_bf, hid_bih_b, gxb, H3, D2);
  k_gru_scan<<<dim3(BB,2),512,0,stream>>>(gxf,gxb,hid_whh_f,hid_whh_b,hid_bhh_f,hid_bhh_b,
                                          hidden,hq,hq_bf,agg_bf,nullptr);

  // ---- projections (concatenated weights: 3 GEMMs instead of 6) ----
  mmbf(hp_bf, WA_bf, nullptr, s1Am, 256, D2);   // [s1 | Am]
  mmbf(hq_bf, WB_bf, nullptr, s2BS, 384, D2);   // [s2 | Bm | spj]
  mmbf(hp_bf, Wb_bf, nullptr, Pb,   D2,  D2);

  // ---- attentions -> agg (bf16). slices: hq(0) pts(256) ptc(512) ptd(768) ptb(1024) ptm(1280)
  dim3 gq(SS,BB);
  k_attn3<<<gq,256,0,stream>>>(s1Am, s2BS, Pb, hq, vc, vm, hp, agg_bf);
  k_mulattn_fused<<<gq,256,0,stream>>>(hp_bf,hq,Wd_bf,vd,hp,agg_bf,768);
  k_mulattn_fused<<<gq,256,0,stream>>>(hq_bf,hq,Ws_bf,vs,hq,agg_bf,256);

  // ---- aggregation BiGRU ----
  mmbf(agg_bf, aggf_bf, agg_bih_f, gxf, H3, D12);
  mmbf(agg_bf, aggb_bf, agg_bih_b, gxb, H3, D12);
  k_gru_scan<<<dim3(BB,2),512,0,stream>>>(gxf,gxb,agg_whh_f,agg_whh_b,agg_bhh_f,agg_bhh_b,
                                          nullptr,agg_rep,aggrep_bf,nullptr,nullptr);

  // ---- pooling + prediction ----
  k_rl<<<BB,256,0,stream>>>(s2BS,hq,vp,Wc2,sB);
  mmbf(aggrep_bf, WA_bf, nullptr, sA, EE, D2);  // Wc1 = first 128 rows of WA
  k_final<<<BB,256,0,stream>>>(sA,sB,vc,agg_rep,Wpred,(float*)d_out);
}